// Round 1
// baseline (12743.219 us; speedup 1.0000x reference)
//
#include <hip/hip_runtime.h>

#define NN 50000
#define NE 800000
#define EPSf 1e-5f

// ---------------- graph normalization ----------------
__global__ void deg_kernel(const int* __restrict__ col, const float* __restrict__ ew,
                           float* __restrict__ deg) {
  int e = blockIdx.x * 256 + threadIdx.x;
  if (e >= NE) return;
  unsafeAtomicAdd(&deg[col[e]], ew[e]);
}

__global__ void dinv_kernel(float* __restrict__ deg) {
  int n = blockIdx.x * 256 + threadIdx.x;
  if (n >= NN) return;
  float d = deg[n];
  deg[n] = d > 0.f ? rsqrtf(d) : 0.f;  // overwrite deg with dinv
}

__global__ void norm_kernel(const int* __restrict__ row, const int* __restrict__ col,
                            const float* __restrict__ ew, const float* __restrict__ dinv,
                            float* __restrict__ nrm) {
  int e = blockIdx.x * 256 + threadIdx.x;
  if (e >= NE) return;
  nrm[e] = dinv[row[e]] * ew[e] * dinv[col[e]];
}

// ---------------- sparse propagation ----------------
// hnew[col] += nrm * h[row], D=64. One thread per (edge, 4-channel chunk).
__global__ void prop64(const int* __restrict__ row, const int* __restrict__ col,
                       const float* __restrict__ nrm, const float* __restrict__ h,
                       float* __restrict__ hn) {
  int idx = blockIdx.x * 256 + threadIdx.x;
  if (idx >= NE * 16) return;
  int e = idx >> 4, q = idx & 15;
  float nm = nrm[e];
  int r = row[e], c = col[e];
  float4 v = *(const float4*)(h + r * 64 + q * 4);
  float* dst = hn + c * 64 + q * 4;
  unsafeAtomicAdd(dst + 0, nm * v.x);
  unsafeAtomicAdd(dst + 1, nm * v.y);
  unsafeAtomicAdd(dst + 2, nm * v.z);
  unsafeAtomicAdd(dst + 3, nm * v.w);
}

// 2-channel variant for the first TAGConv (IN_C = 2)
__global__ void prop2(const int* __restrict__ row, const int* __restrict__ col,
                      const float* __restrict__ nrm, const float* __restrict__ h,
                      float* __restrict__ hn) {
  int e = blockIdx.x * 256 + threadIdx.x;
  if (e >= NE) return;
  float nm = nrm[e];
  int r = row[e], c = col[e];
  unsafeAtomicAdd(&hn[c * 2 + 0], nm * h[r * 2 + 0]);
  unsafeAtomicAdd(&hn[c * 2 + 1], nm * h[r * 2 + 1]);
}

// ---------------- dense GEMMs ----------------
// acc[n][:] (+)= h[n][:] @ W (64x64). Thread per (node, 4 outputs).
__global__ void gemm64(const float* __restrict__ h, const float* __restrict__ W,
                       float* __restrict__ acc, int accum) {
  int idx = blockIdx.x * 256 + threadIdx.x;
  if (idx >= NN * 16) return;
  int n = idx >> 4, q = idx & 15;
  const float* hn = h + n * 64;
  float4 a;
  if (accum) a = ((const float4*)acc)[idx];
  else a = make_float4(0.f, 0.f, 0.f, 0.f);
#pragma unroll 8
  for (int c = 0; c < 64; c++) {
    float hv = hn[c];
    float4 wv = ((const float4*)(W + c * 64))[q];
    a.x += hv * wv.x; a.y += hv * wv.y; a.z += hv * wv.z; a.w += hv * wv.w;
  }
  ((float4*)acc)[idx] = a;
}

// acc[n][:] (+)= h2[n][0:2] @ W (2x64)
__global__ void gemm2(const float* __restrict__ h2, const float* __restrict__ W,
                      float* __restrict__ acc, int accum) {
  int idx = blockIdx.x * 256 + threadIdx.x;
  if (idx >= NN * 16) return;
  int n = idx >> 4, q = idx & 15;
  float x0 = h2[n * 2], x1 = h2[n * 2 + 1];
  float4 w0 = ((const float4*)W)[q];
  float4 w1 = ((const float4*)W)[16 + q];
  float4 a;
  if (accum) a = ((const float4*)acc)[idx];
  else a = make_float4(0.f, 0.f, 0.f, 0.f);
  a.x += x0 * w0.x + x1 * w1.x;
  a.y += x0 * w0.y + x1 * w1.y;
  a.z += x0 * w0.z + x1 * w1.z;
  a.w += x0 * w0.w + x1 * w1.w;
  ((float4*)acc)[idx] = a;
}

// ---------------- InstanceNorm stats ----------------
// st[0:64] = per-channel sum of (acc+bias), st[64:128] = sumsq
__global__ void stats64(const float* __restrict__ acc, const float* __restrict__ bias,
                        float* __restrict__ st) {
  int c = threadIdx.x & 63, g = threadIdx.x >> 6;
  float s = 0.f, ss = 0.f;
  float b = bias[c];
  for (int n = blockIdx.x * 4 + g; n < NN; n += gridDim.x * 4) {
    float v = acc[n * 64 + c] + b;
    s += v; ss += v * v;
  }
  __shared__ float ls[256], lss[256];
  ls[threadIdx.x] = s; lss[threadIdx.x] = ss;
  __syncthreads();
  if (threadIdx.x < 64) {
    s = ls[threadIdx.x] + ls[threadIdx.x + 64] + ls[threadIdx.x + 128] + ls[threadIdx.x + 192];
    ss = lss[threadIdx.x] + lss[threadIdx.x + 64] + lss[threadIdx.x + 128] + lss[threadIdx.x + 192];
    unsafeAtomicAdd(&st[c], s);
    unsafeAtomicAdd(&st[64 + c], ss);
  }
}

// out = [relu]( [inorm](acc + bias) [+ resid] )
__global__ void apply64(const float* __restrict__ acc, const float* __restrict__ bias,
                        const float* __restrict__ st, const float* __restrict__ resid,
                        float* __restrict__ out, int inorm, int relu) {
  int idx = blockIdx.x * 256 + threadIdx.x;
  if (idx >= NN * 16) return;
  int q = idx & 15;
  int c0 = q * 4;
  const float4 av = ((const float4*)acc)[idx];
  float v0 = av.x + bias[c0 + 0];
  float v1 = av.y + bias[c0 + 1];
  float v2 = av.z + bias[c0 + 2];
  float v3 = av.w + bias[c0 + 3];
  if (inorm) {
    const float invN = 1.f / NN;
    float m0 = st[c0 + 0] * invN, m1 = st[c0 + 1] * invN;
    float m2 = st[c0 + 2] * invN, m3 = st[c0 + 3] * invN;
    float r0 = rsqrtf(st[64 + c0 + 0] * invN - m0 * m0 + EPSf);
    float r1 = rsqrtf(st[64 + c0 + 1] * invN - m1 * m1 + EPSf);
    float r2 = rsqrtf(st[64 + c0 + 2] * invN - m2 * m2 + EPSf);
    float r3 = rsqrtf(st[64 + c0 + 3] * invN - m3 * m3 + EPSf);
    v0 = (v0 - m0) * r0; v1 = (v1 - m1) * r1;
    v2 = (v2 - m2) * r2; v3 = (v3 - m3) * r3;
  }
  if (resid) {
    const float4 rv = ((const float4*)resid)[idx];
    v0 += rv.x; v1 += rv.y; v2 += rv.z; v3 += rv.w;
  }
  if (relu) {
    v0 = fmaxf(v0, 0.f); v1 = fmaxf(v1, 0.f);
    v2 = fmaxf(v2, 0.f); v3 = fmaxf(v3, 0.f);
  }
  ((float4*)out)[idx] = make_float4(v0, v1, v2, v3);
}

// ---------------- fused edge MLP ----------------
__global__ void __launch_bounds__(256) edge_mlp(
    const float* __restrict__ dat, const int* __restrict__ row, const int* __restrict__ col,
    const float* __restrict__ ew,
    const float* __restrict__ We0, const float* __restrict__ be0,
    const float* __restrict__ g0, const float* __restrict__ b0,
    const float* __restrict__ Wa, const float* __restrict__ ba,
    const float* __restrict__ Wb, const float* __restrict__ bb,
    const float* __restrict__ lg, const float* __restrict__ lb,
    const float* __restrict__ Wf, const float* __restrict__ bfp,
    float* __restrict__ eout) {
  int e = blockIdx.x * 256 + threadIdx.x;
  if (e >= NE) return;
  const int r = row[e], c = col[e];
  const float w = ew[e];
  float h[64];
#pragma unroll
  for (int d = 0; d < 64; d++) h[d] = be0[d] + w * We0[128 * 64 + d];
  const float4* xr = (const float4*)(dat + r * 64);
  for (int i4 = 0; i4 < 16; i4++) {
    float4 a = xr[i4];
    const float* W0 = We0 + i4 * 4 * 64;
#pragma unroll
    for (int d = 0; d < 64; d++)
      h[d] += a.x * W0[d] + a.y * W0[64 + d] + a.z * W0[128 + d] + a.w * W0[192 + d];
  }
  const float4* xc = (const float4*)(dat + c * 64);
  for (int i4 = 0; i4 < 16; i4++) {
    float4 a = xc[i4];
    const float* W0 = We0 + (64 + i4 * 4) * 64;
#pragma unroll
    for (int d = 0; d < 64; d++)
      h[d] += a.x * W0[d] + a.y * W0[64 + d] + a.z * W0[128 + d] + a.w * W0[192 + d];
  }
  // LayerNorm0 + ReLU
  {
    float m = 0.f;
#pragma unroll
    for (int d = 0; d < 64; d++) m += h[d];
    m *= (1.f / 64);
    float v = 0.f;
#pragma unroll
    for (int d = 0; d < 64; d++) { float u = h[d] - m; v += u * u; }
    float is = rsqrtf(v * (1.f / 64) + EPSf);
#pragma unroll
    for (int d = 0; d < 64; d++) h[d] = fmaxf((h[d] - m) * is * g0[d] + b0[d], 0.f);
  }
  // two residual blocks
  for (int j = 0; j < 2; j++) {
    const float* Waj = Wa + j * 4096; const float* baj = ba + j * 64;
    const float* Wbj = Wb + j * 4096; const float* bbj = bb + j * 64;
    const float* lgj = lg + j * 64;   const float* lbj = lb + j * 64;
    float t[64];
#pragma unroll
    for (int d = 0; d < 64; d++) t[d] = baj[d];
#pragma unroll
    for (int i = 0; i < 64; i++) {
      float hv = h[i];
      const float* Wr = Waj + i * 64;
#pragma unroll
      for (int d = 0; d < 64; d++) t[d] += hv * Wr[d];
    }
#pragma unroll
    for (int d = 0; d < 64; d++) t[d] = fmaxf(t[d], 0.f);
    float h2[64];
#pragma unroll
    for (int d = 0; d < 64; d++) h2[d] = bbj[d];
#pragma unroll
    for (int i = 0; i < 64; i++) {
      float tv = t[i];
      const float* Wr = Wbj + i * 64;
#pragma unroll
      for (int d = 0; d < 64; d++) h2[d] += tv * Wr[d];
    }
    float m = 0.f;
#pragma unroll
    for (int d = 0; d < 64; d++) m += h2[d];
    m *= (1.f / 64);
    float v = 0.f;
#pragma unroll
    for (int d = 0; d < 64; d++) { float u = h2[d] - m; v += u * u; }
    float is = rsqrtf(v * (1.f / 64) + EPSf);
#pragma unroll
    for (int d = 0; d < 64; d++)
      h[d] = fmaxf((h2[d] - m) * is * lgj[d] + lbj[d] + h[d], 0.f);
  }
  float o = bfp[0];
#pragma unroll
  for (int d = 0; d < 64; d++) o += h[d] * Wf[d];
  eout[e] = o;
}

// ---------------- output standardization ----------------
__global__ void reduce2(const float* __restrict__ v, float* __restrict__ est) {
  __shared__ float ls[256], lss[256];
  float s = 0.f, ss = 0.f;
  for (int i = blockIdx.x * 256 + threadIdx.x; i < NE; i += gridDim.x * 256) {
    float a = v[i]; s += a; ss += a * a;
  }
  ls[threadIdx.x] = s; lss[threadIdx.x] = ss;
  __syncthreads();
  for (int o = 128; o > 0; o >>= 1) {
    if (threadIdx.x < o) { ls[threadIdx.x] += ls[threadIdx.x + o]; lss[threadIdx.x] += lss[threadIdx.x + o]; }
    __syncthreads();
  }
  if (threadIdx.x == 0) {
    unsafeAtomicAdd(&est[0], ls[0]);
    unsafeAtomicAdd(&est[1], lss[0]);
  }
}

__global__ void finalize(const float* __restrict__ eo, const float* __restrict__ est,
                         float* __restrict__ out) {
  int e = blockIdx.x * 256 + threadIdx.x;
  if (e >= NE) return;
  float sum = est[0], ssq = est[1];
  float m = sum * (1.f / NE);
  float var = (ssq - sum * sum * (1.f / NE)) * (1.f / (NE - 1));
  out[e] = fabsf((eo[e] - m) * rsqrtf(var));
}

// ---------------- host orchestration ----------------
extern "C" void kernel_launch(void* const* d_in, const int* in_sizes, int n_in,
                              void* d_out, int out_size, void* d_ws, size_t ws_size,
                              hipStream_t stream) {
  const float* x   = (const float*)d_in[0];
  const int*   ei  = (const int*)d_in[1];
  const float* ew  = (const float*)d_in[2];
  const float* t0w = (const float*)d_in[3];
  const float* t0b = (const float*)d_in[4];
  const float* tw  = (const float*)d_in[5];
  const float* tb  = (const float*)d_in[6];
  const float* We0 = (const float*)d_in[7];
  const float* be0 = (const float*)d_in[8];
  const float* g0  = (const float*)d_in[9];
  const float* b0  = (const float*)d_in[10];
  const float* Wa  = (const float*)d_in[11];
  const float* ba  = (const float*)d_in[12];
  const float* Wb  = (const float*)d_in[13];
  const float* bb  = (const float*)d_in[14];
  const float* lg  = (const float*)d_in[15];
  const float* lb  = (const float*)d_in[16];
  const float* Wf  = (const float*)d_in[17];
  const float* bf  = (const float*)d_in[18];
  const int* row = ei;
  const int* col = ei + NE;

  float* ws   = (float*)d_ws;
  float* dinv = ws;                   // NN (deg, then overwritten with dinv)
  float* nrm  = ws + 50048;           // NE
  float* bufA = ws + 850048;          // NN*64
  float* bufB = bufA + 3200000;       // NN*64
  float* acc  = bufB + 3200000;       // NN*64
  float* dat  = acc  + 3200000;       // NN*64
  float* tbuf = dat  + 3200000;       // NN*64
  float* st   = tbuf + 3200000;       // 128
  float* est  = st + 128;             // 2
  float* eout = st + 192;             // NE

  const int B = 256;
  dim3 blk(B);
#define GRID(n) dim3(((n) + 255) / 256)

  // graph normalization
  hipMemsetAsync(dinv, 0, NN * sizeof(float), stream);
  deg_kernel<<<GRID(NE), blk, 0, stream>>>(col, ew, dinv);
  dinv_kernel<<<GRID(NN), blk, 0, stream>>>(dinv);
  norm_kernel<<<GRID(NE), blk, 0, stream>>>(row, col, ew, dinv, nrm);

  // ---- TAGConv 0 (2 -> 64) ----
  gemm2<<<GRID(NN * 16), blk, 0, stream>>>(x, t0w, acc, 0);
  hipMemsetAsync(bufA, 0, NN * 2 * sizeof(float), stream);
  prop2<<<GRID(NE), blk, 0, stream>>>(row, col, nrm, x, bufA);
  gemm2<<<GRID(NN * 16), blk, 0, stream>>>(bufA, t0w + 128, acc, 1);
  hipMemsetAsync(bufB, 0, NN * 2 * sizeof(float), stream);
  prop2<<<GRID(NE), blk, 0, stream>>>(row, col, nrm, bufA, bufB);
  gemm2<<<GRID(NN * 16), blk, 0, stream>>>(bufB, t0w + 256, acc, 1);
  hipMemsetAsync(bufA, 0, NN * 2 * sizeof(float), stream);
  prop2<<<GRID(NE), blk, 0, stream>>>(row, col, nrm, bufB, bufA);
  gemm2<<<GRID(NN * 16), blk, 0, stream>>>(bufA, t0w + 384, acc, 1);
  hipMemsetAsync(st, 0, 128 * sizeof(float), stream);
  stats64<<<dim3(128), blk, 0, stream>>>(acc, t0b, st);
  apply64<<<GRID(NN * 16), blk, 0, stream>>>(acc, t0b, st, nullptr, dat, 1, 1);

  // generic 64-ch tagconv into acc
  auto tagconv64 = [&](const float* src, const float* W) {
    gemm64<<<GRID(NN * 16), blk, 0, stream>>>(src, W, acc, 0);
    hipMemsetAsync(bufA, 0, (size_t)NN * 64 * sizeof(float), stream);
    prop64<<<GRID(NE * 16), blk, 0, stream>>>(row, col, nrm, src, bufA);
    gemm64<<<GRID(NN * 16), blk, 0, stream>>>(bufA, W + 4096, acc, 1);
    hipMemsetAsync(bufB, 0, (size_t)NN * 64 * sizeof(float), stream);
    prop64<<<GRID(NE * 16), blk, 0, stream>>>(row, col, nrm, bufA, bufB);
    gemm64<<<GRID(NN * 16), blk, 0, stream>>>(bufB, W + 8192, acc, 1);
    hipMemsetAsync(bufA, 0, (size_t)NN * 64 * sizeof(float), stream);
    prop64<<<GRID(NE * 16), blk, 0, stream>>>(row, col, nrm, bufB, bufA);
    gemm64<<<GRID(NN * 16), blk, 0, stream>>>(bufA, W + 12288, acc, 1);
  };

  // ---- residual blocks ----
  for (int i = 0; i < 2; i++) {
    tagconv64(dat, tw + (2 * i) * 16384);
    apply64<<<GRID(NN * 16), blk, 0, stream>>>(acc, tb + (2 * i) * 64, nullptr, nullptr, tbuf, 0, 1);
    tagconv64(tbuf, tw + (2 * i + 1) * 16384);
    hipMemsetAsync(st, 0, 128 * sizeof(float), stream);
    stats64<<<dim3(128), blk, 0, stream>>>(acc, tb + (2 * i + 1) * 64, st);
    apply64<<<GRID(NN * 16), blk, 0, stream>>>(acc, tb + (2 * i + 1) * 64, st, dat, dat, 1, 1);
  }
  // ---- final tagconv (no norm) ----
  tagconv64(dat, tw + 4 * 16384);
  apply64<<<GRID(NN * 16), blk, 0, stream>>>(acc, tb + 4 * 64, nullptr, dat, dat, 0, 1);

  // ---- edge MLP ----
  edge_mlp<<<GRID(NE), blk, 0, stream>>>(dat, row, col, ew, We0, be0, g0, b0,
                                         Wa, ba, Wb, bb, lg, lb, Wf, bf, eout);
  hipMemsetAsync(est, 0, 2 * sizeof(float), stream);
  reduce2<<<dim3(1024), blk, 0, stream>>>(eout, est);
  finalize<<<GRID(NE), blk, 0, stream>>>(eout, est, (float*)d_out);
#undef GRID
}

// Round 2
// 2839.013 us; speedup vs baseline: 4.4886x; 4.4886x over previous
//
#include <hip/hip_runtime.h>

#define NN 50000
#define NE 800000
#define EPSf 1e-5f

// ================= graph prep =================
__global__ void deg_hist_kernel(const int* __restrict__ row, const int* __restrict__ col,
                                const float* __restrict__ ew,
                                float* __restrict__ deg, int* __restrict__ cnt) {
  int e = blockIdx.x * 256 + threadIdx.x;
  if (e >= NE) return;
  int c = col[e];
  unsafeAtomicAdd(&deg[c], ew[e]);
  atomicAdd(&cnt[c], 1);
}

__global__ void dinv_kernel(float* __restrict__ deg) {
  int n = blockIdx.x * 256 + threadIdx.x;
  if (n >= NN) return;
  float d = deg[n];
  deg[n] = d > 0.f ? rsqrtf(d) : 0.f;
}

// exclusive scan of cnt (in place) -- 3 kernels
__global__ void scan1(int* __restrict__ cnt, int* __restrict__ aux) {
  __shared__ int ls[256];
  int t = threadIdx.x, idx = blockIdx.x * 256 + t;
  int v = (idx < NN) ? cnt[idx] : 0;
  ls[t] = v;
  __syncthreads();
  for (int o = 1; o < 256; o <<= 1) {
    int u = (t >= o) ? ls[t - o] : 0;
    __syncthreads();
    ls[t] += u;
    __syncthreads();
  }
  if (idx < NN) cnt[idx] = ls[t] - v;           // exclusive
  if (t == 255) aux[blockIdx.x] = ls[255];      // block total
}

__global__ void scan2(int* __restrict__ aux, int nb) {
  __shared__ int ls[256];
  int t = threadIdx.x;
  int v = (t < nb) ? aux[t] : 0;
  ls[t] = v;
  __syncthreads();
  for (int o = 1; o < 256; o <<= 1) {
    int u = (t >= o) ? ls[t - o] : 0;
    __syncthreads();
    ls[t] += u;
    __syncthreads();
  }
  if (t < nb) aux[t] = ls[t] - v;               // exclusive block offsets
}

__global__ void scan3(int* __restrict__ cnt, const int* __restrict__ aux) {
  int idx = blockIdx.x * 256 + threadIdx.x;
  if (idx < NN) cnt[idx] += aux[idx >> 8];
}

// scatter edges sorted by destination; rowptr[c] turns from start into end
__global__ void scatter_kernel(const int* __restrict__ row, const int* __restrict__ col,
                               const float* __restrict__ ew, const float* __restrict__ dinv,
                               int* __restrict__ rowptr, int* __restrict__ srcidx,
                               float* __restrict__ wsrt) {
  int e = blockIdx.x * 256 + threadIdx.x;
  if (e >= NE) return;
  int r = row[e], c = col[e];
  float w = dinv[r] * ew[e] * dinv[c];
  int p = atomicAdd(&rowptr[c], 1);
  srcidx[p] = r;
  wsrt[p] = w;
}

// ================= CSR propagation =================
// hn[n] = sum_{j in in(n)} w_j * h[src_j], D=64, thread per (node, 4ch)
__global__ void prop64_csr(const int* __restrict__ rowptr, const int* __restrict__ srcidx,
                           const float* __restrict__ wsrt, const float* __restrict__ h,
                           float* __restrict__ hn) {
  int idx = blockIdx.x * 256 + threadIdx.x;
  if (idx >= NN * 16) return;
  int n = idx >> 4, q = idx & 15;
  int s = n ? rowptr[n - 1] : 0;
  int epos = rowptr[n];
  float4 a = make_float4(0.f, 0.f, 0.f, 0.f);
  const float4* h4 = (const float4*)h;
  for (int j = s; j < epos; j++) {
    int r = srcidx[j];
    float nm = wsrt[j];
    float4 v = h4[r * 16 + q];
    a.x += nm * v.x; a.y += nm * v.y; a.z += nm * v.z; a.w += nm * v.w;
  }
  ((float4*)hn)[idx] = a;
}

// 2-channel variant, thread per node
__global__ void prop2_csr(const int* __restrict__ rowptr, const int* __restrict__ srcidx,
                          const float* __restrict__ wsrt, const float* __restrict__ h,
                          float* __restrict__ hn) {
  int n = blockIdx.x * 256 + threadIdx.x;
  if (n >= NN) return;
  int s = n ? rowptr[n - 1] : 0;
  int epos = rowptr[n];
  float a0 = 0.f, a1 = 0.f;
  for (int j = s; j < epos; j++) {
    int r = srcidx[j];
    float nm = wsrt[j];
    a0 += nm * h[r * 2 + 0];
    a1 += nm * h[r * 2 + 1];
  }
  hn[n * 2 + 0] = a0;
  hn[n * 2 + 1] = a1;
}

// ================= dense GEMMs =================
// acc[n][:] (+)= h[n][:] @ W(64x64), W staged in LDS, 16 outputs/thread
__global__ void gemm64_lds(const float* __restrict__ h, const float* __restrict__ W,
                           float* __restrict__ acc, int accum) {
  __shared__ float Ws[4096];
  int t = threadIdx.x;
  for (int i = t; i < 1024; i += 256) ((float4*)Ws)[i] = ((const float4*)W)[i];
  __syncthreads();
  int n = blockIdx.x * 64 + (t >> 2);
  if (n >= NN) return;
  int p = t & 3;  // output quad-of-16
  const float4* hn4 = (const float4*)(h + n * 64);
  float4 a0, a1, a2, a3;
  if (accum) {
    const float4* av = (const float4*)(acc + n * 64 + p * 16);
    a0 = av[0]; a1 = av[1]; a2 = av[2]; a3 = av[3];
  } else {
    a0 = a1 = a2 = a3 = make_float4(0.f, 0.f, 0.f, 0.f);
  }
#pragma unroll 4
  for (int c4 = 0; c4 < 16; c4++) {
    float4 hv = hn4[c4];
    const float* wb = Ws + c4 * 256 + p * 16;
#pragma unroll
    for (int k = 0; k < 4; k++) {
      float hk = k == 0 ? hv.x : k == 1 ? hv.y : k == 2 ? hv.z : hv.w;
      const float4* wr = (const float4*)(wb + k * 64);
      float4 w0 = wr[0], w1 = wr[1], w2 = wr[2], w3 = wr[3];
      a0.x += hk * w0.x; a0.y += hk * w0.y; a0.z += hk * w0.z; a0.w += hk * w0.w;
      a1.x += hk * w1.x; a1.y += hk * w1.y; a1.z += hk * w1.z; a1.w += hk * w1.w;
      a2.x += hk * w2.x; a2.y += hk * w2.y; a2.z += hk * w2.z; a2.w += hk * w2.w;
      a3.x += hk * w3.x; a3.y += hk * w3.y; a3.z += hk * w3.z; a3.w += hk * w3.w;
    }
  }
  float4* out = (float4*)(acc + n * 64 + p * 16);
  out[0] = a0; out[1] = a1; out[2] = a2; out[3] = a3;
}

// acc[n][:] (+)= h2[n][0:2] @ W (2x64)
__global__ void gemm2(const float* __restrict__ h2, const float* __restrict__ W,
                      float* __restrict__ acc, int accum) {
  int idx = blockIdx.x * 256 + threadIdx.x;
  if (idx >= NN * 16) return;
  int n = idx >> 4, q = idx & 15;
  float x0 = h2[n * 2], x1 = h2[n * 2 + 1];
  float4 w0 = ((const float4*)W)[q];
  float4 w1 = ((const float4*)W)[16 + q];
  float4 a;
  if (accum) a = ((const float4*)acc)[idx];
  else a = make_float4(0.f, 0.f, 0.f, 0.f);
  a.x += x0 * w0.x + x1 * w1.x;
  a.y += x0 * w0.y + x1 * w1.y;
  a.z += x0 * w0.z + x1 * w1.z;
  a.w += x0 * w0.w + x1 * w1.w;
  ((float4*)acc)[idx] = a;
}

// ================= InstanceNorm =================
__global__ void stats64(const float* __restrict__ acc, const float* __restrict__ bias,
                        float* __restrict__ st) {
  int c = threadIdx.x & 63, g = threadIdx.x >> 6;
  float s = 0.f, ss = 0.f;
  float b = bias[c];
  for (int n = blockIdx.x * 4 + g; n < NN; n += gridDim.x * 4) {
    float v = acc[n * 64 + c] + b;
    s += v; ss += v * v;
  }
  __shared__ float ls[256], lss[256];
  ls[threadIdx.x] = s; lss[threadIdx.x] = ss;
  __syncthreads();
  if (threadIdx.x < 64) {
    s = ls[threadIdx.x] + ls[threadIdx.x + 64] + ls[threadIdx.x + 128] + ls[threadIdx.x + 192];
    ss = lss[threadIdx.x] + lss[threadIdx.x + 64] + lss[threadIdx.x + 128] + lss[threadIdx.x + 192];
    unsafeAtomicAdd(&st[c], s);
    unsafeAtomicAdd(&st[64 + c], ss);
  }
}

__global__ void apply64(const float* __restrict__ acc, const float* __restrict__ bias,
                        const float* __restrict__ st, const float* __restrict__ resid,
                        float* __restrict__ out, int inorm, int relu) {
  int idx = blockIdx.x * 256 + threadIdx.x;
  if (idx >= NN * 16) return;
  int q = idx & 15;
  int c0 = q * 4;
  const float4 av = ((const float4*)acc)[idx];
  float v0 = av.x + bias[c0 + 0];
  float v1 = av.y + bias[c0 + 1];
  float v2 = av.z + bias[c0 + 2];
  float v3 = av.w + bias[c0 + 3];
  if (inorm) {
    const float invN = 1.f / NN;
    float m0 = st[c0 + 0] * invN, m1 = st[c0 + 1] * invN;
    float m2 = st[c0 + 2] * invN, m3 = st[c0 + 3] * invN;
    float r0 = rsqrtf(st[64 + c0 + 0] * invN - m0 * m0 + EPSf);
    float r1 = rsqrtf(st[64 + c0 + 1] * invN - m1 * m1 + EPSf);
    float r2 = rsqrtf(st[64 + c0 + 2] * invN - m2 * m2 + EPSf);
    float r3 = rsqrtf(st[64 + c0 + 3] * invN - m3 * m3 + EPSf);
    v0 = (v0 - m0) * r0; v1 = (v1 - m1) * r1;
    v2 = (v2 - m2) * r2; v3 = (v3 - m3) * r3;
  }
  if (resid) {
    const float4 rv = ((const float4*)resid)[idx];
    v0 += rv.x; v1 += rv.y; v2 += rv.z; v3 += rv.w;
  }
  if (relu) {
    v0 = fmaxf(v0, 0.f); v1 = fmaxf(v1, 0.f);
    v2 = fmaxf(v2, 0.f); v3 = fmaxf(v3, 0.f);
  }
  ((float4*)out)[idx] = make_float4(v0, v1, v2, v3);
}

// ================= fused edge MLP (LDS-staged weights) =================
__global__ void __launch_bounds__(256, 2) edge_mlp(
    const float* __restrict__ dat, const int* __restrict__ row, const int* __restrict__ col,
    const float* __restrict__ ew,
    const float* __restrict__ We0, const float* __restrict__ be0,
    const float* __restrict__ g0, const float* __restrict__ b0,
    const float* __restrict__ Wa, const float* __restrict__ ba,
    const float* __restrict__ Wb, const float* __restrict__ bb,
    const float* __restrict__ lg, const float* __restrict__ lb,
    const float* __restrict__ Wf, const float* __restrict__ bfp,
    float* __restrict__ eout) {
  __shared__ float Ws[8256];  // max(129*64, 2*64*64)
  int t = threadIdx.x;
  // stage We0 (129 x 64)
  for (int i = t; i < 2064; i += 256) ((float4*)Ws)[i] = ((const float4*)We0)[i];
  __syncthreads();

  int e = blockIdx.x * 256 + t;  // NE == 3125*256, no tail
  const int r = row[e], c = col[e];
  const float w = ew[e];
  float h[64];
#pragma unroll
  for (int d = 0; d < 64; d++) h[d] = be0[d] + w * Ws[128 * 64 + d];
  const float4* xr = (const float4*)(dat + r * 64);
#pragma unroll 4
  for (int i4 = 0; i4 < 16; i4++) {
    float4 a = xr[i4];
    const float* W0 = Ws + i4 * 256;
#pragma unroll
    for (int d = 0; d < 64; d++)
      h[d] += a.x * W0[d] + a.y * W0[64 + d] + a.z * W0[128 + d] + a.w * W0[192 + d];
  }
  const float4* xc = (const float4*)(dat + c * 64);
#pragma unroll 4
  for (int i4 = 0; i4 < 16; i4++) {
    float4 a = xc[i4];
    const float* W0 = Ws + 4096 + i4 * 256;
#pragma unroll
    for (int d = 0; d < 64; d++)
      h[d] += a.x * W0[d] + a.y * W0[64 + d] + a.z * W0[128 + d] + a.w * W0[192 + d];
  }
  // LayerNorm0 + ReLU
  {
    float m = 0.f;
#pragma unroll
    for (int d = 0; d < 64; d++) m += h[d];
    m *= (1.f / 64);
    float v = 0.f;
#pragma unroll
    for (int d = 0; d < 64; d++) { float u = h[d] - m; v += u * u; }
    float is = rsqrtf(v * (1.f / 64) + EPSf);
#pragma unroll
    for (int d = 0; d < 64; d++) h[d] = fmaxf((h[d] - m) * is * g0[d] + b0[d], 0.f);
  }
  // two residual blocks; stage Wa[j], Wb[j] per iteration
  for (int j = 0; j < 2; j++) {
    __syncthreads();
    for (int i = t; i < 1024; i += 256) {
      ((float4*)Ws)[i] = ((const float4*)(Wa + j * 4096))[i];
      ((float4*)Ws)[1024 + i] = ((const float4*)(Wb + j * 4096))[i];
    }
    __syncthreads();
    const float* baj = ba + j * 64;
    const float* bbj = bb + j * 64;
    const float* lgj = lg + j * 64;
    const float* lbj = lb + j * 64;
    float tt[64];
#pragma unroll
    for (int d = 0; d < 64; d++) tt[d] = baj[d];
#pragma unroll 4
    for (int i = 0; i < 64; i++) {
      float hv = h[i];
      const float* Wr = Ws + i * 64;
#pragma unroll
      for (int d = 0; d < 64; d++) tt[d] += hv * Wr[d];
    }
#pragma unroll
    for (int d = 0; d < 64; d++) tt[d] = fmaxf(tt[d], 0.f);
    float h2[64];
#pragma unroll
    for (int d = 0; d < 64; d++) h2[d] = bbj[d];
#pragma unroll 4
    for (int i = 0; i < 64; i++) {
      float tv = tt[i];
      const float* Wr = Ws + 4096 + i * 64;
#pragma unroll
      for (int d = 0; d < 64; d++) h2[d] += tv * Wr[d];
    }
    float m = 0.f;
#pragma unroll
    for (int d = 0; d < 64; d++) m += h2[d];
    m *= (1.f / 64);
    float v = 0.f;
#pragma unroll
    for (int d = 0; d < 64; d++) { float u = h2[d] - m; v += u * u; }
    float is = rsqrtf(v * (1.f / 64) + EPSf);
#pragma unroll
    for (int d = 0; d < 64; d++)
      h[d] = fmaxf((h2[d] - m) * is * lgj[d] + lbj[d] + h[d], 0.f);
  }
  float o = bfp[0];
#pragma unroll
  for (int d = 0; d < 64; d++) o += h[d] * Wf[d];
  eout[e] = o;
}

// ================= output standardization =================
__global__ void reduce2(const float* __restrict__ v, float* __restrict__ est) {
  __shared__ float ls[256], lss[256];
  float s = 0.f, ss = 0.f;
  for (int i = blockIdx.x * 256 + threadIdx.x; i < NE; i += gridDim.x * 256) {
    float a = v[i]; s += a; ss += a * a;
  }
  ls[threadIdx.x] = s; lss[threadIdx.x] = ss;
  __syncthreads();
  for (int o = 128; o > 0; o >>= 1) {
    if (threadIdx.x < o) { ls[threadIdx.x] += ls[threadIdx.x + o]; lss[threadIdx.x] += lss[threadIdx.x + o]; }
    __syncthreads();
  }
  if (threadIdx.x == 0) {
    unsafeAtomicAdd(&est[0], ls[0]);
    unsafeAtomicAdd(&est[1], lss[0]);
  }
}

__global__ void finalize(const float* __restrict__ eo, const float* __restrict__ est,
                         float* __restrict__ out) {
  int e = blockIdx.x * 256 + threadIdx.x;
  if (e >= NE) return;
  float sum = est[0], ssq = est[1];
  float m = sum * (1.f / NE);
  float var = (ssq - sum * sum * (1.f / NE)) * (1.f / (NE - 1));
  out[e] = fabsf((eo[e] - m) * rsqrtf(var));
}

// ================= host orchestration =================
extern "C" void kernel_launch(void* const* d_in, const int* in_sizes, int n_in,
                              void* d_out, int out_size, void* d_ws, size_t ws_size,
                              hipStream_t stream) {
  const float* x   = (const float*)d_in[0];
  const int*   ei  = (const int*)d_in[1];
  const float* ew  = (const float*)d_in[2];
  const float* t0w = (const float*)d_in[3];
  const float* t0b = (const float*)d_in[4];
  const float* tw  = (const float*)d_in[5];
  const float* tb  = (const float*)d_in[6];
  const float* We0 = (const float*)d_in[7];
  const float* be0 = (const float*)d_in[8];
  const float* g0  = (const float*)d_in[9];
  const float* b0  = (const float*)d_in[10];
  const float* Wa  = (const float*)d_in[11];
  const float* ba  = (const float*)d_in[12];
  const float* Wb  = (const float*)d_in[13];
  const float* bb  = (const float*)d_in[14];
  const float* lg  = (const float*)d_in[15];
  const float* lb  = (const float*)d_in[16];
  const float* Wf  = (const float*)d_in[17];
  const float* bf  = (const float*)d_in[18];
  const int* row = ei;
  const int* col = ei + NE;

  float* ws = (float*)d_ws;
  // layout (floats): total 17,650,240 == footprint proven in R0
  int*   rowptr = (int*)ws;                  // NN           [0, 50048)
  int*   srcidx = (int*)(ws + 50048);        // NE           [50048, 850048)
  float* wsrt   = ws + 850048;               // NE           [850048, 1650048)
  float* st     = ws + 1650048;              // 192          [1650048, 1650240)
  float* est    = st + 128;                  // 2
  float* bufA   = ws + 1650240;              // NN*64
  float* bufB   = bufA + 3200000;            // NN*64
  float* bufC   = bufB + 3200000;            // NN*64 (tbuf)
  float* acc    = bufC + 3200000;            // NN*64
  float* dat    = acc + 3200000;             // NN*64 -> end 17,650,240
  float* dinv   = bufB;                      // NN, dead after scatter
  int*   aux    = (int*)(bufB + 50048);      // 256, dead after scan
  float* eout   = bufA;                      // NE, edge stage only

  dim3 blk(256);
#define GRID(n) dim3(((n) + 255) / 256)
  const int NB = (NN + 255) / 256;  // 196

  // ---- graph prep: deg + histogram + scan + scatter ----
  hipMemsetAsync(dinv, 0, NN * sizeof(float), stream);
  hipMemsetAsync(rowptr, 0, NN * sizeof(int), stream);
  deg_hist_kernel<<<GRID(NE), blk, 0, stream>>>(row, col, ew, dinv, rowptr);
  dinv_kernel<<<GRID(NN), blk, 0, stream>>>(dinv);
  scan1<<<dim3(NB), blk, 0, stream>>>(rowptr, aux);
  scan2<<<dim3(1), blk, 0, stream>>>(aux, NB);
  scan3<<<dim3(NB), blk, 0, stream>>>(rowptr, aux);
  scatter_kernel<<<GRID(NE), blk, 0, stream>>>(row, col, ew, dinv, rowptr, srcidx, wsrt);
  // rowptr[n] is now END of node n's range; start = rowptr[n-1] (or 0)

  // ---- TAGConv 0 (2 -> 64) ----
  gemm2<<<GRID(NN * 16), blk, 0, stream>>>(x, t0w, acc, 0);
  prop2_csr<<<dim3(NB), blk, 0, stream>>>(rowptr, srcidx, wsrt, x, bufA);
  gemm2<<<GRID(NN * 16), blk, 0, stream>>>(bufA, t0w + 128, acc, 1);
  prop2_csr<<<dim3(NB), blk, 0, stream>>>(rowptr, srcidx, wsrt, bufA, bufB);
  gemm2<<<GRID(NN * 16), blk, 0, stream>>>(bufB, t0w + 256, acc, 1);
  prop2_csr<<<dim3(NB), blk, 0, stream>>>(rowptr, srcidx, wsrt, bufB, bufA);
  gemm2<<<GRID(NN * 16), blk, 0, stream>>>(bufA, t0w + 384, acc, 1);
  hipMemsetAsync(st, 0, 128 * sizeof(float), stream);
  stats64<<<dim3(128), blk, 0, stream>>>(acc, t0b, st);
  apply64<<<GRID(NN * 16), blk, 0, stream>>>(acc, t0b, st, nullptr, dat, 1, 1);

  const int GB = (NN + 63) / 64;  // gemm64 grid: 64 nodes/block
  auto tagconv64 = [&](const float* src, const float* W) {
    gemm64_lds<<<dim3(GB), blk, 0, stream>>>(src, W, acc, 0);
    prop64_csr<<<GRID(NN * 16), blk, 0, stream>>>(rowptr, srcidx, wsrt, src, bufA);
    gemm64_lds<<<dim3(GB), blk, 0, stream>>>(bufA, W + 4096, acc, 1);
    prop64_csr<<<GRID(NN * 16), blk, 0, stream>>>(rowptr, srcidx, wsrt, bufA, bufB);
    gemm64_lds<<<dim3(GB), blk, 0, stream>>>(bufB, W + 8192, acc, 1);
    prop64_csr<<<GRID(NN * 16), blk, 0, stream>>>(rowptr, srcidx, wsrt, bufB, bufA);
    gemm64_lds<<<dim3(GB), blk, 0, stream>>>(bufA, W + 12288, acc, 1);
  };

  // ---- residual blocks ----
  for (int i = 0; i < 2; i++) {
    tagconv64(dat, tw + (2 * i) * 16384);
    apply64<<<GRID(NN * 16), blk, 0, stream>>>(acc, tb + (2 * i) * 64, nullptr, nullptr, bufC, 0, 1);
    tagconv64(bufC, tw + (2 * i + 1) * 16384);
    hipMemsetAsync(st, 0, 128 * sizeof(float), stream);
    stats64<<<dim3(128), blk, 0, stream>>>(acc, tb + (2 * i + 1) * 64, st);
    apply64<<<GRID(NN * 16), blk, 0, stream>>>(acc, tb + (2 * i + 1) * 64, st, dat, dat, 1, 1);
  }
  // ---- final tagconv (no norm) ----
  tagconv64(dat, tw + 4 * 16384);
  apply64<<<GRID(NN * 16), blk, 0, stream>>>(acc, tb + 4 * 64, nullptr, dat, dat, 0, 1);

  // ---- edge MLP ----
  edge_mlp<<<GRID(NE), blk, 0, stream>>>(dat, row, col, ew, We0, be0, g0, b0,
                                         Wa, ba, Wb, bb, lg, lb, Wf, bf, eout);
  hipMemsetAsync(est, 0, 2 * sizeof(float), stream);
  reduce2<<<dim3(1024), blk, 0, stream>>>(eout, est);
  finalize<<<GRID(NE), blk, 0, stream>>>(eout, est, (float*)d_out);
#undef GRID
}

// Round 3
// 2342.020 us; speedup vs baseline: 5.4411x; 1.2122x over previous
//
#include <hip/hip_runtime.h>

#define NN 50000
#define NE 800000
#define EPSf 1e-5f

// ================= graph prep =================
__global__ void deg_hist_kernel(const int* __restrict__ row, const int* __restrict__ col,
                                const float* __restrict__ ew,
                                float* __restrict__ deg, int* __restrict__ cnt) {
  int e = blockIdx.x * 256 + threadIdx.x;
  if (e >= NE) return;
  int c = col[e];
  unsafeAtomicAdd(&deg[c], ew[e]);
  atomicAdd(&cnt[c], 1);
}

__global__ void dinv_kernel(float* __restrict__ deg) {
  int n = blockIdx.x * 256 + threadIdx.x;
  if (n >= NN) return;
  float d = deg[n];
  deg[n] = d > 0.f ? rsqrtf(d) : 0.f;
}

// exclusive scan of cnt (in place) -- 3 kernels
__global__ void scan1(int* __restrict__ cnt, int* __restrict__ aux) {
  __shared__ int ls[256];
  int t = threadIdx.x, idx = blockIdx.x * 256 + t;
  int v = (idx < NN) ? cnt[idx] : 0;
  ls[t] = v;
  __syncthreads();
  for (int o = 1; o < 256; o <<= 1) {
    int u = (t >= o) ? ls[t - o] : 0;
    __syncthreads();
    ls[t] += u;
    __syncthreads();
  }
  if (idx < NN) cnt[idx] = ls[t] - v;           // exclusive
  if (t == 255) aux[blockIdx.x] = ls[255];      // block total
}

__global__ void scan2(int* __restrict__ aux, int nb) {
  __shared__ int ls[256];
  int t = threadIdx.x;
  int v = (t < nb) ? aux[t] : 0;
  ls[t] = v;
  __syncthreads();
  for (int o = 1; o < 256; o <<= 1) {
    int u = (t >= o) ? ls[t - o] : 0;
    __syncthreads();
    ls[t] += u;
    __syncthreads();
  }
  if (t < nb) aux[t] = ls[t] - v;               // exclusive block offsets
}

__global__ void scan3(int* __restrict__ cnt, const int* __restrict__ aux) {
  int idx = blockIdx.x * 256 + threadIdx.x;
  if (idx < NN) cnt[idx] += aux[idx >> 8];
}

// scatter edges sorted by destination; rowptr[c] turns from start into end
__global__ void scatter_kernel(const int* __restrict__ row, const int* __restrict__ col,
                               const float* __restrict__ ew, const float* __restrict__ dinv,
                               int* __restrict__ rowptr, int* __restrict__ srcidx,
                               float* __restrict__ wsrt) {
  int e = blockIdx.x * 256 + threadIdx.x;
  if (e >= NE) return;
  int r = row[e], c = col[e];
  float w = dinv[r] * ew[e] * dinv[c];
  int p = atomicAdd(&rowptr[c], 1);
  srcidx[p] = r;
  wsrt[p] = w;
}

// ================= CSR propagation =================
__global__ void prop64_csr(const int* __restrict__ rowptr, const int* __restrict__ srcidx,
                           const float* __restrict__ wsrt, const float* __restrict__ h,
                           float* __restrict__ hn) {
  int idx = blockIdx.x * 256 + threadIdx.x;
  if (idx >= NN * 16) return;
  int n = idx >> 4, q = idx & 15;
  int s = n ? rowptr[n - 1] : 0;
  int epos = rowptr[n];
  float4 a = make_float4(0.f, 0.f, 0.f, 0.f);
  const float4* h4 = (const float4*)h;
  for (int j = s; j < epos; j++) {
    int r = srcidx[j];
    float nm = wsrt[j];
    float4 v = h4[r * 16 + q];
    a.x += nm * v.x; a.y += nm * v.y; a.z += nm * v.z; a.w += nm * v.w;
  }
  ((float4*)hn)[idx] = a;
}

__global__ void prop2_csr(const int* __restrict__ rowptr, const int* __restrict__ srcidx,
                          const float* __restrict__ wsrt, const float* __restrict__ h,
                          float* __restrict__ hn) {
  int n = blockIdx.x * 256 + threadIdx.x;
  if (n >= NN) return;
  int s = n ? rowptr[n - 1] : 0;
  int epos = rowptr[n];
  float a0 = 0.f, a1 = 0.f;
  for (int j = s; j < epos; j++) {
    int r = srcidx[j];
    float nm = wsrt[j];
    a0 += nm * h[r * 2 + 0];
    a1 += nm * h[r * 2 + 1];
  }
  hn[n * 2 + 0] = a0;
  hn[n * 2 + 1] = a1;
}

// ================= dense GEMMs =================
__global__ void gemm64_lds(const float* __restrict__ h, const float* __restrict__ W,
                           float* __restrict__ acc, int accum) {
  __shared__ float Ws[4096];
  int t = threadIdx.x;
  for (int i = t; i < 1024; i += 256) ((float4*)Ws)[i] = ((const float4*)W)[i];
  __syncthreads();
  int n = blockIdx.x * 64 + (t >> 2);
  if (n >= NN) return;
  int p = t & 3;
  const float4* hn4 = (const float4*)(h + n * 64);
  float4 a0, a1, a2, a3;
  if (accum) {
    const float4* av = (const float4*)(acc + n * 64 + p * 16);
    a0 = av[0]; a1 = av[1]; a2 = av[2]; a3 = av[3];
  } else {
    a0 = a1 = a2 = a3 = make_float4(0.f, 0.f, 0.f, 0.f);
  }
#pragma unroll 4
  for (int c4 = 0; c4 < 16; c4++) {
    float4 hv = hn4[c4];
    const float* wb = Ws + c4 * 256 + p * 16;
#pragma unroll
    for (int k = 0; k < 4; k++) {
      float hk = k == 0 ? hv.x : k == 1 ? hv.y : k == 2 ? hv.z : hv.w;
      const float4* wr = (const float4*)(wb + k * 64);
      float4 w0 = wr[0], w1 = wr[1], w2 = wr[2], w3 = wr[3];
      a0.x += hk * w0.x; a0.y += hk * w0.y; a0.z += hk * w0.z; a0.w += hk * w0.w;
      a1.x += hk * w1.x; a1.y += hk * w1.y; a1.z += hk * w1.z; a1.w += hk * w1.w;
      a2.x += hk * w2.x; a2.y += hk * w2.y; a2.z += hk * w2.z; a2.w += hk * w2.w;
      a3.x += hk * w3.x; a3.y += hk * w3.y; a3.z += hk * w3.z; a3.w += hk * w3.w;
    }
  }
  float4* out = (float4*)(acc + n * 64 + p * 16);
  out[0] = a0; out[1] = a1; out[2] = a2; out[3] = a3;
}

__global__ void gemm2(const float* __restrict__ h2, const float* __restrict__ W,
                      float* __restrict__ acc, int accum) {
  int idx = blockIdx.x * 256 + threadIdx.x;
  if (idx >= NN * 16) return;
  int n = idx >> 4, q = idx & 15;
  float x0 = h2[n * 2], x1 = h2[n * 2 + 1];
  float4 w0 = ((const float4*)W)[q];
  float4 w1 = ((const float4*)W)[16 + q];
  float4 a;
  if (accum) a = ((const float4*)acc)[idx];
  else a = make_float4(0.f, 0.f, 0.f, 0.f);
  a.x += x0 * w0.x + x1 * w1.x;
  a.y += x0 * w0.y + x1 * w1.y;
  a.z += x0 * w0.z + x1 * w1.z;
  a.w += x0 * w0.w + x1 * w1.w;
  ((float4*)acc)[idx] = a;
}

// ================= InstanceNorm =================
__global__ void stats64(const float* __restrict__ acc, const float* __restrict__ bias,
                        float* __restrict__ st) {
  int c = threadIdx.x & 63, g = threadIdx.x >> 6;
  float s = 0.f, ss = 0.f;
  float b = bias[c];
  for (int n = blockIdx.x * 4 + g; n < NN; n += gridDim.x * 4) {
    float v = acc[n * 64 + c] + b;
    s += v; ss += v * v;
  }
  __shared__ float ls[256], lss[256];
  ls[threadIdx.x] = s; lss[threadIdx.x] = ss;
  __syncthreads();
  if (threadIdx.x < 64) {
    s = ls[threadIdx.x] + ls[threadIdx.x + 64] + ls[threadIdx.x + 128] + ls[threadIdx.x + 192];
    ss = lss[threadIdx.x] + lss[threadIdx.x + 64] + lss[threadIdx.x + 128] + lss[threadIdx.x + 192];
    unsafeAtomicAdd(&st[c], s);
    unsafeAtomicAdd(&st[64 + c], ss);
  }
}

__global__ void apply64(const float* __restrict__ acc, const float* __restrict__ bias,
                        const float* __restrict__ st, const float* __restrict__ resid,
                        float* __restrict__ out, int inorm, int relu) {
  int idx = blockIdx.x * 256 + threadIdx.x;
  if (idx >= NN * 16) return;
  int q = idx & 15;
  int c0 = q * 4;
  const float4 av = ((const float4*)acc)[idx];
  float v0 = av.x + bias[c0 + 0];
  float v1 = av.y + bias[c0 + 1];
  float v2 = av.z + bias[c0 + 2];
  float v3 = av.w + bias[c0 + 3];
  if (inorm) {
    const float invN = 1.f / NN;
    float m0 = st[c0 + 0] * invN, m1 = st[c0 + 1] * invN;
    float m2 = st[c0 + 2] * invN, m3 = st[c0 + 3] * invN;
    float r0 = rsqrtf(st[64 + c0 + 0] * invN - m0 * m0 + EPSf);
    float r1 = rsqrtf(st[64 + c0 + 1] * invN - m1 * m1 + EPSf);
    float r2 = rsqrtf(st[64 + c0 + 2] * invN - m2 * m2 + EPSf);
    float r3 = rsqrtf(st[64 + c0 + 3] * invN - m3 * m3 + EPSf);
    v0 = (v0 - m0) * r0; v1 = (v1 - m1) * r1;
    v2 = (v2 - m2) * r2; v3 = (v3 - m3) * r3;
  }
  if (resid) {
    const float4 rv = ((const float4*)resid)[idx];
    v0 += rv.x; v1 += rv.y; v2 += rv.z; v3 += rv.w;
  }
  if (relu) {
    v0 = fmaxf(v0, 0.f); v1 = fmaxf(v1, 0.f);
    v2 = fmaxf(v2, 0.f); v3 = fmaxf(v3, 0.f);
  }
  ((float4*)out)[idx] = make_float4(v0, v1, v2, v3);
}

// ================= fused edge MLP =================
// h (residual vector) lives in registers with STATIC indexing only.
// The GEMM reduction operand lives in LDS (hbuf), runtime-indexable.
// hbuf layout: [16 quads][256 threads][4 floats] -> thread-private column.
__global__ void __launch_bounds__(256, 2) edge_mlp(
    const float* __restrict__ dat, const int* __restrict__ row, const int* __restrict__ col,
    const float* __restrict__ ew,
    const float* __restrict__ We0, const float* __restrict__ be0,
    const float* __restrict__ g0, const float* __restrict__ b0,
    const float* __restrict__ Wa, const float* __restrict__ ba,
    const float* __restrict__ Wb, const float* __restrict__ bb,
    const float* __restrict__ lg, const float* __restrict__ lb,
    const float* __restrict__ Wf, const float* __restrict__ bfp,
    float* __restrict__ eout) {
  __shared__ float Wbuf[4096];    // 16 KB: one 64x64 weight panel
  __shared__ float hbuf[16384];   // 64 KB: per-thread 64-float column
  const int t = threadIdx.x;
  const int e = blockIdx.x * 256 + t;  // NE == 3125*256, no tail
  const int r = row[e], c = col[e];
  const float w = ew[e];

  float h[64];
#pragma unroll
  for (int d = 0; d < 64; d++) h[d] = be0[d] + w * We0[8192 + d];

  // ---- phase 1a: dat[r] @ We0 rows 0..63 ----
  for (int i = t; i < 1024; i += 256) ((float4*)Wbuf)[i] = ((const float4*)We0)[i];
  __syncthreads();
  {
    const float4* xr = (const float4*)(dat + r * 64);
#pragma unroll 1
    for (int i4 = 0; i4 < 16; i4++) {
      float4 a = xr[i4];
      const float* wb = Wbuf + i4 * 256;
#pragma unroll
      for (int d = 0; d < 64; d++)
        h[d] += a.x * wb[d] + a.y * wb[64 + d] + a.z * wb[128 + d] + a.w * wb[192 + d];
    }
  }
  // ---- phase 1b: dat[c] @ We0 rows 64..127 ----
  __syncthreads();
  for (int i = t; i < 1024; i += 256) ((float4*)Wbuf)[i] = ((const float4*)(We0 + 4096))[i];
  __syncthreads();
  {
    const float4* xc = (const float4*)(dat + c * 64);
#pragma unroll 1
    for (int i4 = 0; i4 < 16; i4++) {
      float4 a = xc[i4];
      const float* wb = Wbuf + i4 * 256;
#pragma unroll
      for (int d = 0; d < 64; d++)
        h[d] += a.x * wb[d] + a.y * wb[64 + d] + a.z * wb[128 + d] + a.w * wb[192 + d];
    }
  }
  // ---- LayerNorm0 + ReLU (all static) ----
  {
    float m = 0.f;
#pragma unroll
    for (int d = 0; d < 64; d++) m += h[d];
    m *= (1.f / 64);
    float v = 0.f;
#pragma unroll
    for (int d = 0; d < 64; d++) { float u = h[d] - m; v += u * u; }
    float is = rsqrtf(v * (1.f / 64) + EPSf);
#pragma unroll
    for (int d = 0; d < 64; d++) h[d] = fmaxf((h[d] - m) * is * g0[d] + b0[d], 0.f);
  }
  // write h to private LDS column
#pragma unroll
  for (int i4 = 0; i4 < 16; i4++)
    *(float4*)&hbuf[i4 * 1024 + t * 4] =
        make_float4(h[4 * i4], h[4 * i4 + 1], h[4 * i4 + 2], h[4 * i4 + 3]);

  // ---- two residual blocks ----
#pragma unroll 1
  for (int j = 0; j < 2; j++) {
    __syncthreads();
    for (int i = t; i < 1024; i += 256) ((float4*)Wbuf)[i] = ((const float4*)(Wa + j * 4096))[i];
    __syncthreads();
    float acc[64];
#pragma unroll
    for (int d = 0; d < 64; d++) acc[d] = ba[j * 64 + d];
#pragma unroll 1
    for (int i4 = 0; i4 < 16; i4++) {
      float4 hv = *(const float4*)&hbuf[i4 * 1024 + t * 4];
      const float* wb = Wbuf + i4 * 256;
#pragma unroll
      for (int d = 0; d < 64; d++)
        acc[d] += hv.x * wb[d] + hv.y * wb[64 + d] + hv.z * wb[128 + d] + hv.w * wb[192 + d];
    }
    // t = ReLU(acc) -> LDS column (h stays in registers)
#pragma unroll
    for (int i4 = 0; i4 < 16; i4++)
      *(float4*)&hbuf[i4 * 1024 + t * 4] =
          make_float4(fmaxf(acc[4 * i4], 0.f), fmaxf(acc[4 * i4 + 1], 0.f),
                      fmaxf(acc[4 * i4 + 2], 0.f), fmaxf(acc[4 * i4 + 3], 0.f));
    __syncthreads();
    for (int i = t; i < 1024; i += 256) ((float4*)Wbuf)[i] = ((const float4*)(Wb + j * 4096))[i];
    __syncthreads();
#pragma unroll
    for (int d = 0; d < 64; d++) acc[d] = bb[j * 64 + d];
#pragma unroll 1
    for (int i4 = 0; i4 < 16; i4++) {
      float4 hv = *(const float4*)&hbuf[i4 * 1024 + t * 4];
      const float* wb = Wbuf + i4 * 256;
#pragma unroll
      for (int d = 0; d < 64; d++)
        acc[d] += hv.x * wb[d] + hv.y * wb[64 + d] + hv.z * wb[128 + d] + hv.w * wb[192 + d];
    }
    // LN + residual + ReLU (static)
    float m = 0.f;
#pragma unroll
    for (int d = 0; d < 64; d++) m += acc[d];
    m *= (1.f / 64);
    float v = 0.f;
#pragma unroll
    for (int d = 0; d < 64; d++) { float u = acc[d] - m; v += u * u; }
    float is = rsqrtf(v * (1.f / 64) + EPSf);
#pragma unroll
    for (int d = 0; d < 64; d++)
      h[d] = fmaxf((acc[d] - m) * is * lg[j * 64 + d] + lb[j * 64 + d] + h[d], 0.f);
    if (j == 0) {
#pragma unroll
      for (int i4 = 0; i4 < 16; i4++)
        *(float4*)&hbuf[i4 * 1024 + t * 4] =
            make_float4(h[4 * i4], h[4 * i4 + 1], h[4 * i4 + 2], h[4 * i4 + 3]);
    }
  }
  float o = bfp[0];
#pragma unroll
  for (int d = 0; d < 64; d++) o += h[d] * Wf[d];
  eout[e] = o;
}

// ================= output standardization =================
__global__ void reduce2(const float* __restrict__ v, float* __restrict__ est) {
  __shared__ float ls[256], lss[256];
  float s = 0.f, ss = 0.f;
  for (int i = blockIdx.x * 256 + threadIdx.x; i < NE; i += gridDim.x * 256) {
    float a = v[i]; s += a; ss += a * a;
  }
  ls[threadIdx.x] = s; lss[threadIdx.x] = ss;
  __syncthreads();
  for (int o = 128; o > 0; o >>= 1) {
    if (threadIdx.x < o) { ls[threadIdx.x] += ls[threadIdx.x + o]; lss[threadIdx.x] += lss[threadIdx.x + o]; }
    __syncthreads();
  }
  if (threadIdx.x == 0) {
    unsafeAtomicAdd(&est[0], ls[0]);
    unsafeAtomicAdd(&est[1], lss[0]);
  }
}

__global__ void finalize(const float* __restrict__ eo, const float* __restrict__ est,
                         float* __restrict__ out) {
  int e = blockIdx.x * 256 + threadIdx.x;
  if (e >= NE) return;
  float sum = est[0], ssq = est[1];
  float m = sum * (1.f / NE);
  float var = (ssq - sum * sum * (1.f / NE)) * (1.f / (NE - 1));
  out[e] = fabsf((eo[e] - m) * rsqrtf(var));
}

// ================= host orchestration =================
extern "C" void kernel_launch(void* const* d_in, const int* in_sizes, int n_in,
                              void* d_out, int out_size, void* d_ws, size_t ws_size,
                              hipStream_t stream) {
  const float* x   = (const float*)d_in[0];
  const int*   ei  = (const int*)d_in[1];
  const float* ew  = (const float*)d_in[2];
  const float* t0w = (const float*)d_in[3];
  const float* t0b = (const float*)d_in[4];
  const float* tw  = (const float*)d_in[5];
  const float* tb  = (const float*)d_in[6];
  const float* We0 = (const float*)d_in[7];
  const float* be0 = (const float*)d_in[8];
  const float* g0  = (const float*)d_in[9];
  const float* b0  = (const float*)d_in[10];
  const float* Wa  = (const float*)d_in[11];
  const float* ba  = (const float*)d_in[12];
  const float* Wb  = (const float*)d_in[13];
  const float* bb  = (const float*)d_in[14];
  const float* lg  = (const float*)d_in[15];
  const float* lb  = (const float*)d_in[16];
  const float* Wf  = (const float*)d_in[17];
  const float* bf  = (const float*)d_in[18];
  const int* row = ei;
  const int* col = ei + NE;

  float* ws = (float*)d_ws;
  int*   rowptr = (int*)ws;                  // NN
  int*   srcidx = (int*)(ws + 50048);        // NE
  float* wsrt   = ws + 850048;               // NE
  float* st     = ws + 1650048;              // 192
  float* est    = st + 128;                  // 2
  float* bufA   = ws + 1650240;              // NN*64
  float* bufB   = bufA + 3200000;            // NN*64
  float* bufC   = bufB + 3200000;            // NN*64
  float* acc    = bufC + 3200000;            // NN*64
  float* dat    = acc + 3200000;             // NN*64
  float* dinv   = bufB;                      // NN, dead after scatter
  int*   aux    = (int*)(bufB + 50048);      // 256, dead after scan
  float* eout   = bufA;                      // NE, edge stage only

  dim3 blk(256);
#define GRID(n) dim3(((n) + 255) / 256)
  const int NB = (NN + 255) / 256;  // 196

  // ---- graph prep ----
  hipMemsetAsync(dinv, 0, NN * sizeof(float), stream);
  hipMemsetAsync(rowptr, 0, NN * sizeof(int), stream);
  deg_hist_kernel<<<GRID(NE), blk, 0, stream>>>(row, col, ew, dinv, rowptr);
  dinv_kernel<<<GRID(NN), blk, 0, stream>>>(dinv);
  scan1<<<dim3(NB), blk, 0, stream>>>(rowptr, aux);
  scan2<<<dim3(1), blk, 0, stream>>>(aux, NB);
  scan3<<<dim3(NB), blk, 0, stream>>>(rowptr, aux);
  scatter_kernel<<<GRID(NE), blk, 0, stream>>>(row, col, ew, dinv, rowptr, srcidx, wsrt);

  // ---- TAGConv 0 (2 -> 64) ----
  gemm2<<<GRID(NN * 16), blk, 0, stream>>>(x, t0w, acc, 0);
  prop2_csr<<<dim3(NB), blk, 0, stream>>>(rowptr, srcidx, wsrt, x, bufA);
  gemm2<<<GRID(NN * 16), blk, 0, stream>>>(bufA, t0w + 128, acc, 1);
  prop2_csr<<<dim3(NB), blk, 0, stream>>>(rowptr, srcidx, wsrt, bufA, bufB);
  gemm2<<<GRID(NN * 16), blk, 0, stream>>>(bufB, t0w + 256, acc, 1);
  prop2_csr<<<dim3(NB), blk, 0, stream>>>(rowptr, srcidx, wsrt, bufB, bufA);
  gemm2<<<GRID(NN * 16), blk, 0, stream>>>(bufA, t0w + 384, acc, 1);
  hipMemsetAsync(st, 0, 128 * sizeof(float), stream);
  stats64<<<dim3(128), blk, 0, stream>>>(acc, t0b, st);
  apply64<<<GRID(NN * 16), blk, 0, stream>>>(acc, t0b, st, nullptr, dat, 1, 1);

  const int GB = (NN + 63) / 64;
  auto tagconv64 = [&](const float* src, const float* W) {
    gemm64_lds<<<dim3(GB), blk, 0, stream>>>(src, W, acc, 0);
    prop64_csr<<<GRID(NN * 16), blk, 0, stream>>>(rowptr, srcidx, wsrt, src, bufA);
    gemm64_lds<<<dim3(GB), blk, 0, stream>>>(bufA, W + 4096, acc, 1);
    prop64_csr<<<GRID(NN * 16), blk, 0, stream>>>(rowptr, srcidx, wsrt, bufA, bufB);
    gemm64_lds<<<dim3(GB), blk, 0, stream>>>(bufB, W + 8192, acc, 1);
    prop64_csr<<<GRID(NN * 16), blk, 0, stream>>>(rowptr, srcidx, wsrt, bufB, bufA);
    gemm64_lds<<<dim3(GB), blk, 0, stream>>>(bufA, W + 12288, acc, 1);
  };

  // ---- residual blocks ----
  for (int i = 0; i < 2; i++) {
    tagconv64(dat, tw + (2 * i) * 16384);
    apply64<<<GRID(NN * 16), blk, 0, stream>>>(acc, tb + (2 * i) * 64, nullptr, nullptr, bufC, 0, 1);
    tagconv64(bufC, tw + (2 * i + 1) * 16384);
    hipMemsetAsync(st, 0, 128 * sizeof(float), stream);
    stats64<<<dim3(128), blk, 0, stream>>>(acc, tb + (2 * i + 1) * 64, st);
    apply64<<<GRID(NN * 16), blk, 0, stream>>>(acc, tb + (2 * i + 1) * 64, st, dat, dat, 1, 1);
  }
  // ---- final tagconv (no norm) ----
  tagconv64(dat, tw + 4 * 16384);
  apply64<<<GRID(NN * 16), blk, 0, stream>>>(acc, tb + 4 * 64, nullptr, dat, dat, 0, 1);

  // ---- edge MLP ----
  edge_mlp<<<GRID(NE), blk, 0, stream>>>(dat, row, col, ew, We0, be0, g0, b0,
                                         Wa, ba, Wb, bb, lg, lb, Wf, bf, eout);
  hipMemsetAsync(est, 0, 2 * sizeof(float), stream);
  reduce2<<<dim3(1024), blk, 0, stream>>>(eout, est);
  finalize<<<GRID(NE), blk, 0, stream>>>(eout, est, (float*)d_out);
#undef GRID
}

// Round 4
// 1393.793 us; speedup vs baseline: 9.1428x; 1.6803x over previous
//
#include <hip/hip_runtime.h>

#define NN 50000
#define NE 800000
#define EPSf 1e-5f

typedef _Float16 half8 __attribute__((ext_vector_type(8)));
typedef _Float16 half4v __attribute__((ext_vector_type(4)));
typedef _Float16 half2v __attribute__((ext_vector_type(2)));
typedef float f32x4 __attribute__((ext_vector_type(4)));

#define HA_STRIDE 72    // halves: 64 + 8 pad -> 144B rows (2-way bank alias, free)
#define WT_STRIDE 136   // halves: 128 + 8 pad -> 272B rows

// ================= graph prep =================
__global__ void deg_hist_kernel(const int* __restrict__ row, const int* __restrict__ col,
                                const float* __restrict__ ew,
                                float* __restrict__ deg, int* __restrict__ cnt) {
  int e = blockIdx.x * 256 + threadIdx.x;
  if (e >= NE) return;
  int c = col[e];
  unsafeAtomicAdd(&deg[c], ew[e]);
  atomicAdd(&cnt[c], 1);
}

__global__ void dinv_kernel(float* __restrict__ deg) {
  int n = blockIdx.x * 256 + threadIdx.x;
  if (n >= NN) return;
  float d = deg[n];
  deg[n] = d > 0.f ? rsqrtf(d) : 0.f;
}

__global__ void scan1(int* __restrict__ cnt, int* __restrict__ aux) {
  __shared__ int ls[256];
  int t = threadIdx.x, idx = blockIdx.x * 256 + t;
  int v = (idx < NN) ? cnt[idx] : 0;
  ls[t] = v;
  __syncthreads();
  for (int o = 1; o < 256; o <<= 1) {
    int u = (t >= o) ? ls[t - o] : 0;
    __syncthreads();
    ls[t] += u;
    __syncthreads();
  }
  if (idx < NN) cnt[idx] = ls[t] - v;
  if (t == 255) aux[blockIdx.x] = ls[255];
}

__global__ void scan2(int* __restrict__ aux, int nb) {
  __shared__ int ls[256];
  int t = threadIdx.x;
  int v = (t < nb) ? aux[t] : 0;
  ls[t] = v;
  __syncthreads();
  for (int o = 1; o < 256; o <<= 1) {
    int u = (t >= o) ? ls[t - o] : 0;
    __syncthreads();
    ls[t] += u;
    __syncthreads();
  }
  if (t < nb) aux[t] = ls[t] - v;
}

__global__ void scan3(int* __restrict__ cnt, const int* __restrict__ aux) {
  int idx = blockIdx.x * 256 + threadIdx.x;
  if (idx < NN) cnt[idx] += aux[idx >> 8];
}

__global__ void scatter_kernel(const int* __restrict__ row, const int* __restrict__ col,
                               const float* __restrict__ ew, const float* __restrict__ dinv,
                               int* __restrict__ rowptr, int* __restrict__ srcidx,
                               float* __restrict__ wsrt) {
  int e = blockIdx.x * 256 + threadIdx.x;
  if (e >= NE) return;
  int r = row[e], c = col[e];
  float w = dinv[r] * ew[e] * dinv[c];
  int p = atomicAdd(&rowptr[c], 1);
  srcidx[p] = r;
  wsrt[p] = w;
}

// ================= CSR propagation =================
__global__ void prop64_csr(const int* __restrict__ rowptr, const int* __restrict__ srcidx,
                           const float* __restrict__ wsrt, const float* __restrict__ h,
                           float* __restrict__ hn) {
  int idx = blockIdx.x * 256 + threadIdx.x;
  if (idx >= NN * 16) return;
  int n = idx >> 4, q = idx & 15;
  int s = n ? rowptr[n - 1] : 0;
  int epos = rowptr[n];
  float4 a = make_float4(0.f, 0.f, 0.f, 0.f);
  const float4* h4 = (const float4*)h;
  for (int j = s; j < epos; j++) {
    int r = srcidx[j];
    float nm = wsrt[j];
    float4 v = h4[r * 16 + q];
    a.x += nm * v.x; a.y += nm * v.y; a.z += nm * v.z; a.w += nm * v.w;
  }
  ((float4*)hn)[idx] = a;
}

__global__ void prop2_csr(const int* __restrict__ rowptr, const int* __restrict__ srcidx,
                          const float* __restrict__ wsrt, const float* __restrict__ h,
                          float* __restrict__ hn) {
  int n = blockIdx.x * 256 + threadIdx.x;
  if (n >= NN) return;
  int s = n ? rowptr[n - 1] : 0;
  int epos = rowptr[n];
  float a0 = 0.f, a1 = 0.f;
  for (int j = s; j < epos; j++) {
    int r = srcidx[j];
    float nm = wsrt[j];
    a0 += nm * h[r * 2 + 0];
    a1 += nm * h[r * 2 + 1];
  }
  hn[n * 2 + 0] = a0;
  hn[n * 2 + 1] = a1;
}

// ================= dense node GEMMs =================
__global__ void gemm64_lds(const float* __restrict__ h, const float* __restrict__ W,
                           float* __restrict__ acc, int accum) {
  __shared__ float Ws[4096];
  int t = threadIdx.x;
  for (int i = t; i < 1024; i += 256) ((float4*)Ws)[i] = ((const float4*)W)[i];
  __syncthreads();
  int n = blockIdx.x * 64 + (t >> 2);
  if (n >= NN) return;
  int p = t & 3;
  const float4* hn4 = (const float4*)(h + n * 64);
  float4 a0, a1, a2, a3;
  if (accum) {
    const float4* av = (const float4*)(acc + n * 64 + p * 16);
    a0 = av[0]; a1 = av[1]; a2 = av[2]; a3 = av[3];
  } else {
    a0 = a1 = a2 = a3 = make_float4(0.f, 0.f, 0.f, 0.f);
  }
#pragma unroll 4
  for (int c4 = 0; c4 < 16; c4++) {
    float4 hv = hn4[c4];
    const float* wb = Ws + c4 * 256 + p * 16;
#pragma unroll
    for (int k = 0; k < 4; k++) {
      float hk = k == 0 ? hv.x : k == 1 ? hv.y : k == 2 ? hv.z : hv.w;
      const float4* wr = (const float4*)(wb + k * 64);
      float4 w0 = wr[0], w1 = wr[1], w2 = wr[2], w3 = wr[3];
      a0.x += hk * w0.x; a0.y += hk * w0.y; a0.z += hk * w0.z; a0.w += hk * w0.w;
      a1.x += hk * w1.x; a1.y += hk * w1.y; a1.z += hk * w1.z; a1.w += hk * w1.w;
      a2.x += hk * w2.x; a2.y += hk * w2.y; a2.z += hk * w2.z; a2.w += hk * w2.w;
      a3.x += hk * w3.x; a3.y += hk * w3.y; a3.z += hk * w3.z; a3.w += hk * w3.w;
    }
  }
  float4* out = (float4*)(acc + n * 64 + p * 16);
  out[0] = a0; out[1] = a1; out[2] = a2; out[3] = a3;
}

__global__ void gemm2(const float* __restrict__ h2, const float* __restrict__ W,
                      float* __restrict__ acc, int accum) {
  int idx = blockIdx.x * 256 + threadIdx.x;
  if (idx >= NN * 16) return;
  int n = idx >> 4, q = idx & 15;
  float x0 = h2[n * 2], x1 = h2[n * 2 + 1];
  float4 w0 = ((const float4*)W)[q];
  float4 w1 = ((const float4*)W)[16 + q];
  float4 a;
  if (accum) a = ((const float4*)acc)[idx];
  else a = make_float4(0.f, 0.f, 0.f, 0.f);
  a.x += x0 * w0.x + x1 * w1.x;
  a.y += x0 * w0.y + x1 * w1.y;
  a.z += x0 * w0.z + x1 * w1.z;
  a.w += x0 * w0.w + x1 * w1.w;
  ((float4*)acc)[idx] = a;
}

// ================= InstanceNorm =================
__global__ void stats64(const float* __restrict__ acc, const float* __restrict__ bias,
                        float* __restrict__ st) {
  int c = threadIdx.x & 63, g = threadIdx.x >> 6;
  float s = 0.f, ss = 0.f;
  float b = bias[c];
  for (int n = blockIdx.x * 4 + g; n < NN; n += gridDim.x * 4) {
    float v = acc[n * 64 + c] + b;
    s += v; ss += v * v;
  }
  __shared__ float ls[256], lss[256];
  ls[threadIdx.x] = s; lss[threadIdx.x] = ss;
  __syncthreads();
  if (threadIdx.x < 64) {
    s = ls[threadIdx.x] + ls[threadIdx.x + 64] + ls[threadIdx.x + 128] + ls[threadIdx.x + 192];
    ss = lss[threadIdx.x] + lss[threadIdx.x + 64] + lss[threadIdx.x + 128] + lss[threadIdx.x + 192];
    unsafeAtomicAdd(&st[c], s);
    unsafeAtomicAdd(&st[64 + c], ss);
  }
}

__global__ void apply64(const float* __restrict__ acc, const float* __restrict__ bias,
                        const float* __restrict__ st, const float* __restrict__ resid,
                        float* __restrict__ out, int inorm, int relu) {
  int idx = blockIdx.x * 256 + threadIdx.x;
  if (idx >= NN * 16) return;
  int q = idx & 15;
  int c0 = q * 4;
  const float4 av = ((const float4*)acc)[idx];
  float v0 = av.x + bias[c0 + 0];
  float v1 = av.y + bias[c0 + 1];
  float v2 = av.z + bias[c0 + 2];
  float v3 = av.w + bias[c0 + 3];
  if (inorm) {
    const float invN = 1.f / NN;
    float m0 = st[c0 + 0] * invN, m1 = st[c0 + 1] * invN;
    float m2 = st[c0 + 2] * invN, m3 = st[c0 + 3] * invN;
    float r0 = rsqrtf(st[64 + c0 + 0] * invN - m0 * m0 + EPSf);
    float r1 = rsqrtf(st[64 + c0 + 1] * invN - m1 * m1 + EPSf);
    float r2 = rsqrtf(st[64 + c0 + 2] * invN - m2 * m2 + EPSf);
    float r3 = rsqrtf(st[64 + c0 + 3] * invN - m3 * m3 + EPSf);
    v0 = (v0 - m0) * r0; v1 = (v1 - m1) * r1;
    v2 = (v2 - m2) * r2; v3 = (v3 - m3) * r3;
  }
  if (resid) {
    const float4 rv = ((const float4*)resid)[idx];
    v0 += rv.x; v1 += rv.y; v2 += rv.z; v3 += rv.w;
  }
  if (relu) {
    v0 = fmaxf(v0, 0.f); v1 = fmaxf(v1, 0.f);
    v2 = fmaxf(v2, 0.f); v3 = fmaxf(v3, 0.f);
  }
  ((float4*)out)[idx] = make_float4(v0, v1, v2, v3);
}

// ================= MFMA edge MLP =================
// Per block: 256 edges, 4 waves x 64 edges. GEMMs computed as D^T = mfma(WT, h):
// lane owns edge (ct*16 + (lane&15)) and channels (16*nt + 4*(lane>>4) + r).
// Row ops (LayerNorm) = in-lane partials + shfl_xor(16) + shfl_xor(32).
__device__ __forceinline__ void gemm64_step(f32x4 (&acc)[4][4],
                                            const _Float16* hAp, const _Float16* WTp,
                                            int wv, int a, int g, int koff) {
#pragma unroll
  for (int ks = 0; ks < 2; ks++) {
    half8 wf[4], hf[4];
#pragma unroll
    for (int nt = 0; nt < 4; nt++)
      wf[nt] = *(const half8*)&WTp[(nt * 16 + a) * WT_STRIDE + koff + ks * 32 + g * 8];
#pragma unroll
    for (int ct = 0; ct < 4; ct++)
      hf[ct] = *(const half8*)&hAp[(wv * 64 + ct * 16 + a) * HA_STRIDE + ks * 32 + g * 8];
#pragma unroll
    for (int ct = 0; ct < 4; ct++)
#pragma unroll
      for (int nt = 0; nt < 4; nt++)
        acc[ct][nt] = __builtin_amdgcn_mfma_f32_16x16x32_f16(wf[nt], hf[ct], acc[ct][nt], 0, 0, 0);
  }
}

__global__ void __launch_bounds__(256, 2) edge_mlp_mfma(
    const float* __restrict__ dat, const int* __restrict__ row, const int* __restrict__ col,
    const float* __restrict__ ew,
    const float* __restrict__ We0, const float* __restrict__ be0,
    const float* __restrict__ g0, const float* __restrict__ b0,
    const float* __restrict__ Wa, const float* __restrict__ ba,
    const float* __restrict__ Wb, const float* __restrict__ bb,
    const float* __restrict__ lg, const float* __restrict__ lb,
    const float* __restrict__ Wf, const float* __restrict__ bfp,
    float* __restrict__ eout) {
  __shared__ __align__(16) _Float16 hA[256 * HA_STRIDE];  // 36864 B
  __shared__ __align__(16) _Float16 WT[64 * WT_STRIDE];   // 17408 B
  __shared__ float sew[256];

  const int t = threadIdx.x;
  const int lane = t & 63, wv = t >> 6;
  const int a = lane & 15, g = lane >> 4;
  const int eb = blockIdx.x * 256;

  // ---- stage: hA <- f16(dat[row[e]]), sew <- ew, WT <- f16(We0^T) k=0..127 ----
  {
    int e = eb + t;
    sew[t] = ew[e];
    int r = row[e];
    const float4* src = (const float4*)(dat + r * 64);
#pragma unroll
    for (int i = 0; i < 8; i++) {
      float4 x0 = src[2 * i], x1 = src[2 * i + 1];
      half8 hh = {(_Float16)x0.x, (_Float16)x0.y, (_Float16)x0.z, (_Float16)x0.w,
                  (_Float16)x1.x, (_Float16)x1.y, (_Float16)x1.z, (_Float16)x1.w};
      *(half8*)&hA[t * HA_STRIDE + i * 8] = hh;
    }
    int n = t >> 2, kb = (t & 3) * 32;
#pragma unroll
    for (int k2 = 0; k2 < 16; k2++) {
      int k = kb + 2 * k2;
      half2v p = {(_Float16)We0[k * 64 + n], (_Float16)We0[(k + 1) * 64 + n]};
      *(half2v*)&WT[n * WT_STRIDE + k] = p;
    }
  }

  f32x4 be0v[4], w128v[4], g0v[4], b0v[4];
#pragma unroll
  for (int nt = 0; nt < 4; nt++) {
    int ch = nt * 16 + g * 4;
    be0v[nt] = *(const f32x4*)&be0[ch];
    w128v[nt] = *(const f32x4*)&We0[128 * 64 + ch];
    g0v[nt] = *(const f32x4*)&g0[ch];
    b0v[nt] = *(const f32x4*)&b0[ch];
  }

  __syncthreads();

  // ---- phase 1: h1 = [dat_r | dat_c | ew] @ We0 + be0 ----
  f32x4 acc[4][4];
#pragma unroll
  for (int ct = 0; ct < 4; ct++) {
    float we = sew[wv * 64 + ct * 16 + a];
#pragma unroll
    for (int nt = 0; nt < 4; nt++) acc[ct][nt] = be0v[nt] + we * w128v[nt];
  }
  gemm64_step(acc, hA, WT, wv, a, g, 0);
  __syncthreads();
  {
    int e = eb + t;
    int c = col[e];
    const float4* src = (const float4*)(dat + c * 64);
#pragma unroll
    for (int i = 0; i < 8; i++) {
      float4 x0 = src[2 * i], x1 = src[2 * i + 1];
      half8 hh = {(_Float16)x0.x, (_Float16)x0.y, (_Float16)x0.z, (_Float16)x0.w,
                  (_Float16)x1.x, (_Float16)x1.y, (_Float16)x1.z, (_Float16)x1.w};
      *(half8*)&hA[t * HA_STRIDE + i * 8] = hh;
    }
  }
  __syncthreads();
  gemm64_step(acc, hA, WT, wv, a, g, 64);

  // ---- LayerNorm0 + ReLU -> h (f32 registers) ----
  f32x4 h[4][4];
#pragma unroll
  for (int ct = 0; ct < 4; ct++) {
    float s = 0.f, ss = 0.f;
#pragma unroll
    for (int nt = 0; nt < 4; nt++)
#pragma unroll
      for (int r = 0; r < 4; r++) { float v = acc[ct][nt][r]; s += v; ss += v * v; }
    s += __shfl_xor(s, 16); ss += __shfl_xor(ss, 16);
    s += __shfl_xor(s, 32); ss += __shfl_xor(ss, 32);
    float m = s * (1.f / 64);
    float is = rsqrtf(ss * (1.f / 64) - m * m + EPSf);
#pragma unroll
    for (int nt = 0; nt < 4; nt++)
#pragma unroll
      for (int r = 0; r < 4; r++)
        h[ct][nt][r] = fmaxf((acc[ct][nt][r] - m) * is * g0v[nt][r] + b0v[nt][r], 0.f);
  }
  __syncthreads();  // all reads of hA/WT complete

  // ---- residual blocks ----
#pragma unroll 1
  for (int j = 0; j < 2; j++) {
    // stage WT <- Wa[j]; write h -> hA
    {
      const float* W = Wa + j * 4096;
      int n = t >> 2, kb = (t & 3) * 16;
#pragma unroll
      for (int k2 = 0; k2 < 8; k2++) {
        int k = kb + 2 * k2;
        half2v p = {(_Float16)W[k * 64 + n], (_Float16)W[(k + 1) * 64 + n]};
        *(half2v*)&WT[n * WT_STRIDE + k] = p;
      }
    }
#pragma unroll
    for (int ct = 0; ct < 4; ct++)
#pragma unroll
      for (int nt = 0; nt < 4; nt++) {
        half4v hh = {(_Float16)h[ct][nt][0], (_Float16)h[ct][nt][1],
                     (_Float16)h[ct][nt][2], (_Float16)h[ct][nt][3]};
        *(half4v*)&hA[(wv * 64 + ct * 16 + a) * HA_STRIDE + nt * 16 + g * 4] = hh;
      }
    __syncthreads();
    f32x4 accT[4][4];
#pragma unroll
    for (int nt = 0; nt < 4; nt++) {
      f32x4 bv = *(const f32x4*)&ba[j * 64 + nt * 16 + g * 4];
#pragma unroll
      for (int ct = 0; ct < 4; ct++) accT[ct][nt] = bv;
    }
    gemm64_step(accT, hA, WT, wv, a, g, 0);
    __syncthreads();
    // stage WT <- Wb[j]; write relu(accT) -> hA
    {
      const float* W = Wb + j * 4096;
      int n = t >> 2, kb = (t & 3) * 16;
#pragma unroll
      for (int k2 = 0; k2 < 8; k2++) {
        int k = kb + 2 * k2;
        half2v p = {(_Float16)W[k * 64 + n], (_Float16)W[(k + 1) * 64 + n]};
        *(half2v*)&WT[n * WT_STRIDE + k] = p;
      }
    }
#pragma unroll
    for (int ct = 0; ct < 4; ct++)
#pragma unroll
      for (int nt = 0; nt < 4; nt++) {
        half4v hh = {(_Float16)fmaxf(accT[ct][nt][0], 0.f), (_Float16)fmaxf(accT[ct][nt][1], 0.f),
                     (_Float16)fmaxf(accT[ct][nt][2], 0.f), (_Float16)fmaxf(accT[ct][nt][3], 0.f)};
        *(half4v*)&hA[(wv * 64 + ct * 16 + a) * HA_STRIDE + nt * 16 + g * 4] = hh;
      }
    __syncthreads();
    f32x4 accB[4][4];
#pragma unroll
    for (int nt = 0; nt < 4; nt++) {
      f32x4 bv = *(const f32x4*)&bb[j * 64 + nt * 16 + g * 4];
#pragma unroll
      for (int ct = 0; ct < 4; ct++) accB[ct][nt] = bv;
    }
    gemm64_step(accB, hA, WT, wv, a, g, 0);

    f32x4 lgv[4], lbv[4];
#pragma unroll
    for (int nt = 0; nt < 4; nt++) {
      lgv[nt] = *(const f32x4*)&lg[j * 64 + nt * 16 + g * 4];
      lbv[nt] = *(const f32x4*)&lb[j * 64 + nt * 16 + g * 4];
    }
#pragma unroll
    for (int ct = 0; ct < 4; ct++) {
      float s = 0.f, ss = 0.f;
#pragma unroll
      for (int nt = 0; nt < 4; nt++)
#pragma unroll
        for (int r = 0; r < 4; r++) { float v = accB[ct][nt][r]; s += v; ss += v * v; }
      s += __shfl_xor(s, 16); ss += __shfl_xor(ss, 16);
      s += __shfl_xor(s, 32); ss += __shfl_xor(ss, 32);
      float m = s * (1.f / 64);
      float is = rsqrtf(ss * (1.f / 64) - m * m + EPSf);
#pragma unroll
      for (int nt = 0; nt < 4; nt++)
#pragma unroll
        for (int r = 0; r < 4; r++)
          h[ct][nt][r] =
              fmaxf((accB[ct][nt][r] - m) * is * lgv[nt][r] + lbv[nt][r] + h[ct][nt][r], 0.f);
    }
    __syncthreads();
  }

  // ---- final: out = h . Wf + bf ----
  f32x4 wfv[4];
#pragma unroll
  for (int nt = 0; nt < 4; nt++) wfv[nt] = *(const f32x4*)&Wf[nt * 16 + g * 4];
  float p0 = 0.f, p1 = 0.f, p2 = 0.f, p3 = 0.f;
#pragma unroll
  for (int nt = 0; nt < 4; nt++)
#pragma unroll
    for (int r = 0; r < 4; r++) {
      p0 += h[0][nt][r] * wfv[nt][r];
      p1 += h[1][nt][r] * wfv[nt][r];
      p2 += h[2][nt][r] * wfv[nt][r];
      p3 += h[3][nt][r] * wfv[nt][r];
    }
  p0 += __shfl_xor(p0, 16); p0 += __shfl_xor(p0, 32);
  p1 += __shfl_xor(p1, 16); p1 += __shfl_xor(p1, 32);
  p2 += __shfl_xor(p2, 16); p2 += __shfl_xor(p2, 32);
  p3 += __shfl_xor(p3, 16); p3 += __shfl_xor(p3, 32);
  float sel = (g == 0) ? p0 : (g == 1) ? p1 : (g == 2) ? p2 : p3;
  eout[eb + t] = sel + bfp[0];
}

// ================= output standardization =================
__global__ void reduce2(const float* __restrict__ v, float* __restrict__ est) {
  __shared__ float ls[256], lss[256];
  float s = 0.f, ss = 0.f;
  for (int i = blockIdx.x * 256 + threadIdx.x; i < NE; i += gridDim.x * 256) {
    float a = v[i]; s += a; ss += a * a;
  }
  ls[threadIdx.x] = s; lss[threadIdx.x] = ss;
  __syncthreads();
  for (int o = 128; o > 0; o >>= 1) {
    if (threadIdx.x < o) { ls[threadIdx.x] += ls[threadIdx.x + o]; lss[threadIdx.x] += lss[threadIdx.x + o]; }
    __syncthreads();
  }
  if (threadIdx.x == 0) {
    unsafeAtomicAdd(&est[0], ls[0]);
    unsafeAtomicAdd(&est[1], lss[0]);
  }
}

__global__ void finalize(const float* __restrict__ eo, const float* __restrict__ est,
                         float* __restrict__ out) {
  int e = blockIdx.x * 256 + threadIdx.x;
  if (e >= NE) return;
  float sum = est[0], ssq = est[1];
  float m = sum * (1.f / NE);
  float var = (ssq - sum * sum * (1.f / NE)) * (1.f / (NE - 1));
  out[e] = fabsf((eo[e] - m) * rsqrtf(var));
}

// ================= host orchestration =================
extern "C" void kernel_launch(void* const* d_in, const int* in_sizes, int n_in,
                              void* d_out, int out_size, void* d_ws, size_t ws_size,
                              hipStream_t stream) {
  const float* x   = (const float*)d_in[0];
  const int*   ei  = (const int*)d_in[1];
  const float* ew  = (const float*)d_in[2];
  const float* t0w = (const float*)d_in[3];
  const float* t0b = (const float*)d_in[4];
  const float* tw  = (const float*)d_in[5];
  const float* tb  = (const float*)d_in[6];
  const float* We0 = (const float*)d_in[7];
  const float* be0 = (const float*)d_in[8];
  const float* g0  = (const float*)d_in[9];
  const float* b0  = (const float*)d_in[10];
  const float* Wa  = (const float*)d_in[11];
  const float* ba  = (const float*)d_in[12];
  const float* Wb  = (const float*)d_in[13];
  const float* bb  = (const float*)d_in[14];
  const float* lg  = (const float*)d_in[15];
  const float* lb  = (const float*)d_in[16];
  const float* Wf  = (const float*)d_in[17];
  const float* bf  = (const float*)d_in[18];
  const int* row = ei;
  const int* col = ei + NE;

  float* ws = (float*)d_ws;
  int*   rowptr = (int*)ws;                  // NN
  int*   srcidx = (int*)(ws + 50048);        // NE
  float* wsrt   = ws + 850048;               // NE
  float* st     = ws + 1650048;              // 192
  float* est    = st + 128;                  // 2
  float* bufA   = ws + 1650240;              // NN*64
  float* bufB   = bufA + 3200000;            // NN*64
  float* bufC   = bufB + 3200000;            // NN*64
  float* acc    = bufC + 3200000;            // NN*64
  float* dat    = acc + 3200000;             // NN*64
  float* dinv   = bufB;                      // NN, dead after scatter
  int*   aux    = (int*)(bufB + 50048);      // 256, dead after scan
  float* eout   = bufA;                      // NE, edge stage only

  dim3 blk(256);
#define GRID(n) dim3(((n) + 255) / 256)
  const int NB = (NN + 255) / 256;  // 196

  // ---- graph prep ----
  hipMemsetAsync(dinv, 0, NN * sizeof(float), stream);
  hipMemsetAsync(rowptr, 0, NN * sizeof(int), stream);
  deg_hist_kernel<<<GRID(NE), blk, 0, stream>>>(row, col, ew, dinv, rowptr);
  dinv_kernel<<<GRID(NN), blk, 0, stream>>>(dinv);
  scan1<<<dim3(NB), blk, 0, stream>>>(rowptr, aux);
  scan2<<<dim3(1), blk, 0, stream>>>(aux, NB);
  scan3<<<dim3(NB), blk, 0, stream>>>(rowptr, aux);
  scatter_kernel<<<GRID(NE), blk, 0, stream>>>(row, col, ew, dinv, rowptr, srcidx, wsrt);

  // ---- TAGConv 0 (2 -> 64) ----
  gemm2<<<GRID(NN * 16), blk, 0, stream>>>(x, t0w, acc, 0);
  prop2_csr<<<dim3(NB), blk, 0, stream>>>(rowptr, srcidx, wsrt, x, bufA);
  gemm2<<<GRID(NN * 16), blk, 0, stream>>>(bufA, t0w + 128, acc, 1);
  prop2_csr<<<dim3(NB), blk, 0, stream>>>(rowptr, srcidx, wsrt, bufA, bufB);
  gemm2<<<GRID(NN * 16), blk, 0, stream>>>(bufB, t0w + 256, acc, 1);
  prop2_csr<<<dim3(NB), blk, 0, stream>>>(rowptr, srcidx, wsrt, bufB, bufA);
  gemm2<<<GRID(NN * 16), blk, 0, stream>>>(bufA, t0w + 384, acc, 1);
  hipMemsetAsync(st, 0, 128 * sizeof(float), stream);
  stats64<<<dim3(128), blk, 0, stream>>>(acc, t0b, st);
  apply64<<<GRID(NN * 16), blk, 0, stream>>>(acc, t0b, st, nullptr, dat, 1, 1);

  const int GB = (NN + 63) / 64;
  auto tagconv64 = [&](const float* src, const float* W) {
    gemm64_lds<<<dim3(GB), blk, 0, stream>>>(src, W, acc, 0);
    prop64_csr<<<GRID(NN * 16), blk, 0, stream>>>(rowptr, srcidx, wsrt, src, bufA);
    gemm64_lds<<<dim3(GB), blk, 0, stream>>>(bufA, W + 4096, acc, 1);
    prop64_csr<<<GRID(NN * 16), blk, 0, stream>>>(rowptr, srcidx, wsrt, bufA, bufB);
    gemm64_lds<<<dim3(GB), blk, 0, stream>>>(bufB, W + 8192, acc, 1);
    prop64_csr<<<GRID(NN * 16), blk, 0, stream>>>(rowptr, srcidx, wsrt, bufB, bufA);
    gemm64_lds<<<dim3(GB), blk, 0, stream>>>(bufA, W + 12288, acc, 1);
  };

  // ---- residual blocks ----
  for (int i = 0; i < 2; i++) {
    tagconv64(dat, tw + (2 * i) * 16384);
    apply64<<<GRID(NN * 16), blk, 0, stream>>>(acc, tb + (2 * i) * 64, nullptr, nullptr, bufC, 0, 1);
    tagconv64(bufC, tw + (2 * i + 1) * 16384);
    hipMemsetAsync(st, 0, 128 * sizeof(float), stream);
    stats64<<<dim3(128), blk, 0, stream>>>(acc, tb + (2 * i + 1) * 64, st);
    apply64<<<GRID(NN * 16), blk, 0, stream>>>(acc, tb + (2 * i + 1) * 64, st, dat, dat, 1, 1);
  }
  // ---- final tagconv (no norm) ----
  tagconv64(dat, tw + 4 * 16384);
  apply64<<<GRID(NN * 16), blk, 0, stream>>>(acc, tb + 4 * 64, nullptr, dat, dat, 0, 1);

  // ---- edge MLP (MFMA) ----
  edge_mlp_mfma<<<GRID(NE), blk, 0, stream>>>(dat, row, col, ew, We0, be0, g0, b0,
                                              Wa, ba, Wb, bb, lg, lb, Wf, bf, eout);
  hipMemsetAsync(est, 0, 2 * sizeof(float), stream);
  reduce2<<<dim3(1024), blk, 0, stream>>>(eout, est);
  finalize<<<GRID(NE), blk, 0, stream>>>(eout, est, (float*)d_out);
#undef GRID
}

// Round 5
// 886.680 us; speedup vs baseline: 14.3718x; 1.5719x over previous
//
#include <hip/hip_runtime.h>

#define NN 50000
#define NE 800000
#define EPSf 1e-5f

typedef _Float16 half8 __attribute__((ext_vector_type(8)));
typedef _Float16 half4v __attribute__((ext_vector_type(4)));
typedef _Float16 half2v __attribute__((ext_vector_type(2)));
typedef float f32x4 __attribute__((ext_vector_type(4)));

#define HA_STRIDE 72    // halves: 64 + 8 pad
#define WT_STRIDE 136   // halves: 128 + 8 pad
#define WB_STRIDE 72    // halves: 64 + 8 pad (K=64 panels)

// ================= graph prep =================
__global__ void deg_hist_kernel(const int* __restrict__ row, const int* __restrict__ col,
                                const float* __restrict__ ew,
                                float* __restrict__ deg, int* __restrict__ cnt) {
  int e = blockIdx.x * 256 + threadIdx.x;
  if (e >= NE) return;
  int c = col[e];
  unsafeAtomicAdd(&deg[c], ew[e]);
  atomicAdd(&cnt[c], 1);
}

__global__ void dinv_kernel(float* __restrict__ deg) {
  int n = blockIdx.x * 256 + threadIdx.x;
  if (n >= NN) return;
  float d = deg[n];
  deg[n] = d > 0.f ? rsqrtf(d) : 0.f;
}

__global__ void scan1(int* __restrict__ cnt, int* __restrict__ aux) {
  __shared__ int ls[256];
  int t = threadIdx.x, idx = blockIdx.x * 256 + t;
  int v = (idx < NN) ? cnt[idx] : 0;
  ls[t] = v;
  __syncthreads();
  for (int o = 1; o < 256; o <<= 1) {
    int u = (t >= o) ? ls[t - o] : 0;
    __syncthreads();
    ls[t] += u;
    __syncthreads();
  }
  if (idx < NN) cnt[idx] = ls[t] - v;
  if (t == 255) aux[blockIdx.x] = ls[255];
}

__global__ void scan2(int* __restrict__ aux, int nb) {
  __shared__ int ls[256];
  int t = threadIdx.x;
  int v = (t < nb) ? aux[t] : 0;
  ls[t] = v;
  __syncthreads();
  for (int o = 1; o < 256; o <<= 1) {
    int u = (t >= o) ? ls[t - o] : 0;
    __syncthreads();
    ls[t] += u;
    __syncthreads();
  }
  if (t < nb) aux[t] = ls[t] - v;
}

__global__ void scan3(int* __restrict__ cnt, const int* __restrict__ aux) {
  int idx = blockIdx.x * 256 + threadIdx.x;
  if (idx < NN) cnt[idx] += aux[idx >> 8];
}

__global__ void scatter_kernel(const int* __restrict__ row, const int* __restrict__ col,
                               const float* __restrict__ ew, const float* __restrict__ dinv,
                               int* __restrict__ rowptr, int2* __restrict__ pme) {
  int e = blockIdx.x * 256 + threadIdx.x;
  if (e >= NE) return;
  int r = row[e], c = col[e];
  float w = dinv[r] * ew[e] * dinv[c];
  int p = atomicAdd(&rowptr[c], 1);
  pme[p] = make_int2(r, __float_as_int(w));
}

// ================= CSR propagation (f16 features) =================
// thread per (node, 8-channel chunk); 8 lanes share a node's edge list.
__global__ void prop16(const int* __restrict__ rowptr, const int2* __restrict__ pme,
                       const _Float16* __restrict__ h, _Float16* __restrict__ hn) {
  int idx = blockIdx.x * 256 + threadIdx.x;
  if (idx >= NN * 8) return;
  int n = idx >> 3, q = idx & 7;
  int s = n ? rowptr[n - 1] : 0;
  int epos = rowptr[n];
  float a0 = 0.f, a1 = 0.f, a2 = 0.f, a3 = 0.f, a4 = 0.f, a5 = 0.f, a6 = 0.f, a7 = 0.f;
  for (int j = s; j < epos; j++) {
    int2 m = pme[j];
    float w = __int_as_float(m.y);
    half8 v = *(const half8*)&h[(size_t)m.x * 64 + q * 8];
    a0 += w * (float)v[0]; a1 += w * (float)v[1];
    a2 += w * (float)v[2]; a3 += w * (float)v[3];
    a4 += w * (float)v[4]; a5 += w * (float)v[5];
    a6 += w * (float)v[6]; a7 += w * (float)v[7];
  }
  half8 o = {(_Float16)a0, (_Float16)a1, (_Float16)a2, (_Float16)a3,
             (_Float16)a4, (_Float16)a5, (_Float16)a6, (_Float16)a7};
  *(half8*)&hn[(size_t)n * 64 + q * 8] = o;
}

// 2-channel f32 variant for TAGConv0
__global__ void prop2_csr(const int* __restrict__ rowptr, const int2* __restrict__ pme,
                          const float* __restrict__ h, float* __restrict__ hn) {
  int n = blockIdx.x * 256 + threadIdx.x;
  if (n >= NN) return;
  int s = n ? rowptr[n - 1] : 0;
  int epos = rowptr[n];
  float a0 = 0.f, a1 = 0.f;
  for (int j = s; j < epos; j++) {
    int2 m = pme[j];
    float w = __int_as_float(m.y);
    a0 += w * h[m.x * 2 + 0];
    a1 += w * h[m.x * 2 + 1];
  }
  hn[n * 2 + 0] = a0;
  hn[n * 2 + 1] = a1;
}

// ================= batched node GEMM (MFMA): acc = sum_k h_k @ W[k] =================
// block: 128 threads = 2 waves, 128 nodes. D^T = mfma(WT, h): lane owns node
// (wv*64+ct*16+a) and channels (nt*16+g*4+r).
__global__ void __launch_bounds__(128, 4) gemmB_mfma(
    const _Float16* __restrict__ h0, const _Float16* __restrict__ h1,
    const _Float16* __restrict__ h2, const _Float16* __restrict__ h3,
    const float* __restrict__ W,  // [4][64][64] f32, W[k][i][out]
    float* __restrict__ accG) {
  __shared__ __align__(16) _Float16 hA[128 * HA_STRIDE];  // 18432 B
  __shared__ __align__(16) _Float16 WT[64 * WB_STRIDE];   // 9216 B
  const int t = threadIdx.x;
  const int lane = t & 63, wv = t >> 6;
  const int a = lane & 15, g = lane >> 4;
  const int nb = blockIdx.x * 128;
  const _Float16* hs[4] = {h0, h1, h2, h3};

  f32x4 acc[4][4];
#pragma unroll
  for (int ct = 0; ct < 4; ct++)
#pragma unroll
    for (int nt = 0; nt < 4; nt++) acc[ct][nt] = (f32x4)0.f;

#pragma unroll 1
  for (int k = 0; k < 4; k++) {
    const _Float16* hk = hs[k];
    // stage node rows (thread t <-> node nb+t)
    {
      size_t base = (size_t)(nb + t) * 64;
#pragma unroll
      for (int i = 0; i < 8; i++)
        *(half8*)&hA[t * HA_STRIDE + i * 8] = *(const half8*)&hk[base + i * 8];
    }
    // stage WT[out][i] = f16(W[k][i][out])
    {
      const float* Wk = W + k * 4096;
      int n = t >> 1, kb = (t & 1) * 32;
#pragma unroll
      for (int k2 = 0; k2 < 16; k2++) {
        int kk = kb + 2 * k2;
        half2v p = {(_Float16)Wk[kk * 64 + n], (_Float16)Wk[(kk + 1) * 64 + n]};
        *(half2v*)&WT[n * WB_STRIDE + kk] = p;
      }
    }
    __syncthreads();
#pragma unroll
    for (int ks = 0; ks < 2; ks++) {
      half8 wf[4], hf[4];
#pragma unroll
      for (int nt = 0; nt < 4; nt++)
        wf[nt] = *(const half8*)&WT[(nt * 16 + a) * WB_STRIDE + ks * 32 + g * 8];
#pragma unroll
      for (int ct = 0; ct < 4; ct++)
        hf[ct] = *(const half8*)&hA[(wv * 64 + ct * 16 + a) * HA_STRIDE + ks * 32 + g * 8];
#pragma unroll
      for (int ct = 0; ct < 4; ct++)
#pragma unroll
        for (int nt = 0; nt < 4; nt++)
          acc[ct][nt] = __builtin_amdgcn_mfma_f32_16x16x32_f16(wf[nt], hf[ct], acc[ct][nt], 0, 0, 0);
    }
    __syncthreads();
  }
#pragma unroll
  for (int ct = 0; ct < 4; ct++) {
    int node = nb + wv * 64 + ct * 16 + a;
    if (node < NN) {
#pragma unroll
      for (int nt = 0; nt < 4; nt++)
        *(f32x4*)&accG[(size_t)node * 64 + nt * 16 + g * 4] = acc[ct][nt];
    }
  }
}

// 2-ch input GEMM (TAGConv0), f32
__global__ void gemm2(const float* __restrict__ h2, const float* __restrict__ W,
                      float* __restrict__ acc, int accum) {
  int idx = blockIdx.x * 256 + threadIdx.x;
  if (idx >= NN * 16) return;
  int n = idx >> 4, q = idx & 15;
  float x0 = h2[n * 2], x1 = h2[n * 2 + 1];
  float4 w0 = ((const float4*)W)[q];
  float4 w1 = ((const float4*)W)[16 + q];
  float4 a;
  if (accum) a = ((const float4*)acc)[idx];
  else a = make_float4(0.f, 0.f, 0.f, 0.f);
  a.x += x0 * w0.x + x1 * w1.x;
  a.y += x0 * w0.y + x1 * w1.y;
  a.z += x0 * w0.z + x1 * w1.z;
  a.w += x0 * w0.w + x1 * w1.w;
  ((float4*)acc)[idx] = a;
}

// ================= InstanceNorm (bias-free: shift-invariant) =================
__global__ void stats64(const float* __restrict__ acc, float* __restrict__ st) {
  int c = threadIdx.x & 63, g = threadIdx.x >> 6;
  float s = 0.f, ss = 0.f;
  for (int n = blockIdx.x * 4 + g; n < NN; n += gridDim.x * 4) {
    float v = acc[n * 64 + c];
    s += v; ss += v * v;
  }
  __shared__ float ls[256], lss[256];
  ls[threadIdx.x] = s; lss[threadIdx.x] = ss;
  __syncthreads();
  if (threadIdx.x < 64) {
    s = ls[threadIdx.x] + ls[threadIdx.x + 64] + ls[threadIdx.x + 128] + ls[threadIdx.x + 192];
    ss = lss[threadIdx.x] + lss[threadIdx.x + 64] + lss[threadIdx.x + 128] + lss[threadIdx.x + 192];
    unsafeAtomicAdd(&st[c], s);
    unsafeAtomicAdd(&st[64 + c], ss);
  }
}

// out = [relu]( inorm(acc) | (acc+bias) [+resid] ), writes f32 and/or f16
__global__ void apply64(const float* __restrict__ acc, const float* __restrict__ bias,
                        const float* __restrict__ st, const float* __restrict__ resid,
                        float* __restrict__ out32, _Float16* __restrict__ out16,
                        int inorm, int relu) {
  int idx = blockIdx.x * 256 + threadIdx.x;
  if (idx >= NN * 16) return;
  int q = idx & 15;
  int c0 = q * 4;
  const float4 av = ((const float4*)acc)[idx];
  float v0 = av.x, v1 = av.y, v2 = av.z, v3 = av.w;
  if (inorm) {
    const float invN = 1.f / NN;
    float m0 = st[c0 + 0] * invN, m1 = st[c0 + 1] * invN;
    float m2 = st[c0 + 2] * invN, m3 = st[c0 + 3] * invN;
    float r0 = rsqrtf(st[64 + c0 + 0] * invN - m0 * m0 + EPSf);
    float r1 = rsqrtf(st[64 + c0 + 1] * invN - m1 * m1 + EPSf);
    float r2 = rsqrtf(st[64 + c0 + 2] * invN - m2 * m2 + EPSf);
    float r3 = rsqrtf(st[64 + c0 + 3] * invN - m3 * m3 + EPSf);
    v0 = (v0 - m0) * r0; v1 = (v1 - m1) * r1;
    v2 = (v2 - m2) * r2; v3 = (v3 - m3) * r3;
  } else {
    v0 += bias[c0 + 0]; v1 += bias[c0 + 1]; v2 += bias[c0 + 2]; v3 += bias[c0 + 3];
  }
  if (resid) {
    const float4 rv = ((const float4*)resid)[idx];
    v0 += rv.x; v1 += rv.y; v2 += rv.z; v3 += rv.w;
  }
  if (relu) {
    v0 = fmaxf(v0, 0.f); v1 = fmaxf(v1, 0.f);
    v2 = fmaxf(v2, 0.f); v3 = fmaxf(v3, 0.f);
  }
  if (out32) ((float4*)out32)[idx] = make_float4(v0, v1, v2, v3);
  if (out16) {
    half4v hh = {(_Float16)v0, (_Float16)v1, (_Float16)v2, (_Float16)v3};
    *(half4v*)&out16[(size_t)idx * 4] = hh;
  }
}

// ================= MFMA edge MLP =================
__device__ __forceinline__ void gemm64_step(f32x4 (&acc)[4][4],
                                            const _Float16* hAp, const _Float16* WTp,
                                            int wv, int a, int g, int koff) {
#pragma unroll
  for (int ks = 0; ks < 2; ks++) {
    half8 wf[4], hf[4];
#pragma unroll
    for (int nt = 0; nt < 4; nt++)
      wf[nt] = *(const half8*)&WTp[(nt * 16 + a) * WT_STRIDE + koff + ks * 32 + g * 8];
#pragma unroll
    for (int ct = 0; ct < 4; ct++)
      hf[ct] = *(const half8*)&hAp[(wv * 64 + ct * 16 + a) * HA_STRIDE + ks * 32 + g * 8];
#pragma unroll
    for (int ct = 0; ct < 4; ct++)
#pragma unroll
      for (int nt = 0; nt < 4; nt++)
        acc[ct][nt] = __builtin_amdgcn_mfma_f32_16x16x32_f16(wf[nt], hf[ct], acc[ct][nt], 0, 0, 0);
  }
}

__global__ void __launch_bounds__(256, 2) edge_mlp_mfma(
    const _Float16* __restrict__ dat16, const int* __restrict__ row, const int* __restrict__ col,
    const float* __restrict__ ew,
    const float* __restrict__ We0, const float* __restrict__ be0,
    const float* __restrict__ g0, const float* __restrict__ b0,
    const float* __restrict__ Wa, const float* __restrict__ ba,
    const float* __restrict__ Wb, const float* __restrict__ bb,
    const float* __restrict__ lg, const float* __restrict__ lb,
    const float* __restrict__ Wf, const float* __restrict__ bfp,
    float* __restrict__ eout) {
  __shared__ __align__(16) _Float16 hA[256 * HA_STRIDE];  // 36864 B
  __shared__ __align__(16) _Float16 WT[64 * WT_STRIDE];   // 17408 B
  __shared__ float sew[256];

  const int t = threadIdx.x;
  const int lane = t & 63, wv = t >> 6;
  const int a = lane & 15, g = lane >> 4;
  const int eb = blockIdx.x * 256;

  // ---- stage: hA <- dat16[row[e]], sew <- ew, WT <- f16(We0^T) k=0..127 ----
  {
    int e = eb + t;
    sew[t] = ew[e];
    int r = row[e];
    const _Float16* srcp = dat16 + (size_t)r * 64;
#pragma unroll
    for (int i = 0; i < 8; i++)
      *(half8*)&hA[t * HA_STRIDE + i * 8] = *(const half8*)&srcp[i * 8];
    int n = t >> 2, kb = (t & 3) * 32;
#pragma unroll
    for (int k2 = 0; k2 < 16; k2++) {
      int k = kb + 2 * k2;
      half2v p = {(_Float16)We0[k * 64 + n], (_Float16)We0[(k + 1) * 64 + n]};
      *(half2v*)&WT[n * WT_STRIDE + k] = p;
    }
  }

  f32x4 be0v[4], w128v[4], g0v[4], b0v[4];
#pragma unroll
  for (int nt = 0; nt < 4; nt++) {
    int ch = nt * 16 + g * 4;
    be0v[nt] = *(const f32x4*)&be0[ch];
    w128v[nt] = *(const f32x4*)&We0[128 * 64 + ch];
    g0v[nt] = *(const f32x4*)&g0[ch];
    b0v[nt] = *(const f32x4*)&b0[ch];
  }

  __syncthreads();

  // ---- phase 1: h1 = [dat_r | dat_c | ew] @ We0 + be0 ----
  f32x4 acc[4][4];
#pragma unroll
  for (int ct = 0; ct < 4; ct++) {
    float we = sew[wv * 64 + ct * 16 + a];
#pragma unroll
    for (int nt = 0; nt < 4; nt++) acc[ct][nt] = be0v[nt] + we * w128v[nt];
  }
  gemm64_step(acc, hA, WT, wv, a, g, 0);
  __syncthreads();
  {
    int e = eb + t;
    int c = col[e];
    const _Float16* srcp = dat16 + (size_t)c * 64;
#pragma unroll
    for (int i = 0; i < 8; i++)
      *(half8*)&hA[t * HA_STRIDE + i * 8] = *(const half8*)&srcp[i * 8];
  }
  __syncthreads();
  gemm64_step(acc, hA, WT, wv, a, g, 64);

  // ---- LayerNorm0 + ReLU -> h (f32 registers) ----
  f32x4 h[4][4];
#pragma unroll
  for (int ct = 0; ct < 4; ct++) {
    float s = 0.f, ss = 0.f;
#pragma unroll
    for (int nt = 0; nt < 4; nt++)
#pragma unroll
      for (int r = 0; r < 4; r++) { float v = acc[ct][nt][r]; s += v; ss += v * v; }
    s += __shfl_xor(s, 16); ss += __shfl_xor(ss, 16);
    s += __shfl_xor(s, 32); ss += __shfl_xor(ss, 32);
    float m = s * (1.f / 64);
    float is = rsqrtf(ss * (1.f / 64) - m * m + EPSf);
#pragma unroll
    for (int nt = 0; nt < 4; nt++)
#pragma unroll
      for (int r = 0; r < 4; r++)
        h[ct][nt][r] = fmaxf((acc[ct][nt][r] - m) * is * g0v[nt][r] + b0v[nt][r], 0.f);
  }
  __syncthreads();

  // ---- residual blocks ----
#pragma unroll 1
  for (int j = 0; j < 2; j++) {
    {
      const float* W = Wa + j * 4096;
      int n = t >> 2, kb = (t & 3) * 16;
#pragma unroll
      for (int k2 = 0; k2 < 8; k2++) {
        int k = kb + 2 * k2;
        half2v p = {(_Float16)W[k * 64 + n], (_Float16)W[(k + 1) * 64 + n]};
        *(half2v*)&WT[n * WT_STRIDE + k] = p;
      }
    }
#pragma unroll
    for (int ct = 0; ct < 4; ct++)
#pragma unroll
      for (int nt = 0; nt < 4; nt++) {
        half4v hh = {(_Float16)h[ct][nt][0], (_Float16)h[ct][nt][1],
                     (_Float16)h[ct][nt][2], (_Float16)h[ct][nt][3]};
        *(half4v*)&hA[(wv * 64 + ct * 16 + a) * HA_STRIDE + nt * 16 + g * 4] = hh;
      }
    __syncthreads();
    f32x4 accT[4][4];
#pragma unroll
    for (int nt = 0; nt < 4; nt++) {
      f32x4 bv = *(const f32x4*)&ba[j * 64 + nt * 16 + g * 4];
#pragma unroll
      for (int ct = 0; ct < 4; ct++) accT[ct][nt] = bv;
    }
    gemm64_step(accT, hA, WT, wv, a, g, 0);
    __syncthreads();
    {
      const float* W = Wb + j * 4096;
      int n = t >> 2, kb = (t & 3) * 16;
#pragma unroll
      for (int k2 = 0; k2 < 8; k2++) {
        int k = kb + 2 * k2;
        half2v p = {(_Float16)W[k * 64 + n], (_Float16)W[(k + 1) * 64 + n]};
        *(half2v*)&WT[n * WT_STRIDE + k] = p;
      }
    }
#pragma unroll
    for (int ct = 0; ct < 4; ct++)
#pragma unroll
      for (int nt = 0; nt < 4; nt++) {
        half4v hh = {(_Float16)fmaxf(accT[ct][nt][0], 0.f), (_Float16)fmaxf(accT[ct][nt][1], 0.f),
                     (_Float16)fmaxf(accT[ct][nt][2], 0.f), (_Float16)fmaxf(accT[ct][nt][3], 0.f)};
        *(half4v*)&hA[(wv * 64 + ct * 16 + a) * HA_STRIDE + nt * 16 + g * 4] = hh;
      }
    __syncthreads();
    f32x4 accB[4][4];
#pragma unroll
    for (int nt = 0; nt < 4; nt++) {
      f32x4 bv = *(const f32x4*)&bb[j * 64 + nt * 16 + g * 4];
#pragma unroll
      for (int ct = 0; ct < 4; ct++) accB[ct][nt] = bv;
    }
    gemm64_step(accB, hA, WT, wv, a, g, 0);

    f32x4 lgv[4], lbv[4];
#pragma unroll
    for (int nt = 0; nt < 4; nt++) {
      lgv[nt] = *(const f32x4*)&lg[j * 64 + nt * 16 + g * 4];
      lbv[nt] = *(const f32x4*)&lb[j * 64 + nt * 16 + g * 4];
    }
#pragma unroll
    for (int ct = 0; ct < 4; ct++) {
      float s = 0.f, ss = 0.f;
#pragma unroll
      for (int nt = 0; nt < 4; nt++)
#pragma unroll
        for (int r = 0; r < 4; r++) { float v = accB[ct][nt][r]; s += v; ss += v * v; }
      s += __shfl_xor(s, 16); ss += __shfl_xor(ss, 16);
      s += __shfl_xor(s, 32); ss += __shfl_xor(ss, 32);
      float m = s * (1.f / 64);
      float is = rsqrtf(ss * (1.f / 64) - m * m + EPSf);
#pragma unroll
      for (int nt = 0; nt < 4; nt++)
#pragma unroll
        for (int r = 0; r < 4; r++)
          h[ct][nt][r] =
              fmaxf((accB[ct][nt][r] - m) * is * lgv[nt][r] + lbv[nt][r] + h[ct][nt][r], 0.f);
    }
    __syncthreads();
  }

  // ---- final: out = h . Wf + bf ----
  f32x4 wfv[4];
#pragma unroll
  for (int nt = 0; nt < 4; nt++) wfv[nt] = *(const f32x4*)&Wf[nt * 16 + g * 4];
  float p0 = 0.f, p1 = 0.f, p2 = 0.f, p3 = 0.f;
#pragma unroll
  for (int nt = 0; nt < 4; nt++)
#pragma unroll
    for (int r = 0; r < 4; r++) {
      p0 += h[0][nt][r] * wfv[nt][r];
      p1 += h[1][nt][r] * wfv[nt][r];
      p2 += h[2][nt][r] * wfv[nt][r];
      p3 += h[3][nt][r] * wfv[nt][r];
    }
  p0 += __shfl_xor(p0, 16); p0 += __shfl_xor(p0, 32);
  p1 += __shfl_xor(p1, 16); p1 += __shfl_xor(p1, 32);
  p2 += __shfl_xor(p2, 16); p2 += __shfl_xor(p2, 32);
  p3 += __shfl_xor(p3, 16); p3 += __shfl_xor(p3, 32);
  float sel = (g == 0) ? p0 : (g == 1) ? p1 : (g == 2) ? p2 : p3;
  eout[eb + t] = sel + bfp[0];
}

// ================= output standardization =================
__global__ void reduce2(const float* __restrict__ v, float* __restrict__ est) {
  __shared__ float ls[256], lss[256];
  float s = 0.f, ss = 0.f;
  for (int i = blockIdx.x * 256 + threadIdx.x; i < NE; i += gridDim.x * 256) {
    float a = v[i]; s += a; ss += a * a;
  }
  ls[threadIdx.x] = s; lss[threadIdx.x] = ss;
  __syncthreads();
  for (int o = 128; o > 0; o >>= 1) {
    if (threadIdx.x < o) { ls[threadIdx.x] += ls[threadIdx.x + o]; lss[threadIdx.x] += lss[threadIdx.x + o]; }
    __syncthreads();
  }
  if (threadIdx.x == 0) {
    unsafeAtomicAdd(&est[0], ls[0]);
    unsafeAtomicAdd(&est[1], lss[0]);
  }
}

__global__ void finalize(const float* __restrict__ eo, const float* __restrict__ est,
                         float* __restrict__ out) {
  int e = blockIdx.x * 256 + threadIdx.x;
  if (e >= NE) return;
  float sum = est[0], ssq = est[1];
  float m = sum * (1.f / NE);
  float var = (ssq - sum * sum * (1.f / NE)) * (1.f / (NE - 1));
  out[e] = fabsf((eo[e] - m) * rsqrtf(var));
}

// ================= host orchestration =================
extern "C" void kernel_launch(void* const* d_in, const int* in_sizes, int n_in,
                              void* d_out, int out_size, void* d_ws, size_t ws_size,
                              hipStream_t stream) {
  const float* x   = (const float*)d_in[0];
  const int*   ei  = (const int*)d_in[1];
  const float* ew  = (const float*)d_in[2];
  const float* t0w = (const float*)d_in[3];
  const float* t0b = (const float*)d_in[4];
  const float* tw  = (const float*)d_in[5];
  const float* tb  = (const float*)d_in[6];
  const float* We0 = (const float*)d_in[7];
  const float* be0 = (const float*)d_in[8];
  const float* g0  = (const float*)d_in[9];
  const float* b0  = (const float*)d_in[10];
  const float* Wa  = (const float*)d_in[11];
  const float* ba  = (const float*)d_in[12];
  const float* Wb  = (const float*)d_in[13];
  const float* bb  = (const float*)d_in[14];
  const float* lg  = (const float*)d_in[15];
  const float* lb  = (const float*)d_in[16];
  const float* Wf  = (const float*)d_in[17];
  const float* bf  = (const float*)d_in[18];
  const int* row = ei;
  const int* col = ei + NE;

  float* ws = (float*)d_ws;
  // layout (float units)
  int*       rowptr = (int*)ws;                        // NN            [0, 50048)
  int2*      pme    = (int2*)(ws + 50048);             // NE int2       [50048, 1650048)
  float*     st     = ws + 1650048;                    // 192
  float*     est    = st + 128;
  float*     acc    = ws + 1650240;                    // NN*64 f32
  float*     dat    = acc + 3200000;                   // NN*64 f32
  _Float16*  cur16  = (_Float16*)(ws + 8050240);       // NN*64 f16
  _Float16*  mid16  = (_Float16*)(ws + 9650240);       // NN*64 f16
  _Float16*  h1     = (_Float16*)(ws + 11250240);      // NN*64 f16
  _Float16*  h2     = (_Float16*)(ws + 12850240);      // NN*64 f16
  _Float16*  h3     = (_Float16*)(ws + 14450240);      // NN*64 f16
  float*     eout   = ws + 16050240;                   // NE f32
  float*     dinv   = ws + 11250240;                   // alias h1 (prep only)
  int*       aux    = (int*)(ws + 12850240);           // alias h2 (prep only)
  float*     b2a    = ws + 14450240;                   // alias h3 (TAGConv0 only)
  float*     b2b    = b2a + 100096;

  dim3 blk(256);
#define GRID(n) dim3(((n) + 255) / 256)
  const int NB = (NN + 255) / 256;  // 196

  // ---- graph prep ----
  hipMemsetAsync(dinv, 0, NN * sizeof(float), stream);
  hipMemsetAsync(rowptr, 0, NN * sizeof(int), stream);
  deg_hist_kernel<<<GRID(NE), blk, 0, stream>>>(row, col, ew, dinv, rowptr);
  dinv_kernel<<<GRID(NN), blk, 0, stream>>>(dinv);
  scan1<<<dim3(NB), blk, 0, stream>>>(rowptr, aux);
  scan2<<<dim3(1), blk, 0, stream>>>(aux, NB);
  scan3<<<dim3(NB), blk, 0, stream>>>(rowptr, aux);
  scatter_kernel<<<GRID(NE), blk, 0, stream>>>(row, col, ew, dinv, rowptr, pme);

  // ---- TAGConv 0 (2 -> 64, f32) ----
  gemm2<<<GRID(NN * 16), blk, 0, stream>>>(x, t0w, acc, 0);
  prop2_csr<<<dim3(NB), blk, 0, stream>>>(rowptr, pme, x, b2a);
  gemm2<<<GRID(NN * 16), blk, 0, stream>>>(b2a, t0w + 128, acc, 1);
  prop2_csr<<<dim3(NB), blk, 0, stream>>>(rowptr, pme, b2a, b2b);
  gemm2<<<GRID(NN * 16), blk, 0, stream>>>(b2b, t0w + 256, acc, 1);
  prop2_csr<<<dim3(NB), blk, 0, stream>>>(rowptr, pme, b2b, b2a);
  gemm2<<<GRID(NN * 16), blk, 0, stream>>>(b2a, t0w + 384, acc, 1);
  hipMemsetAsync(st, 0, 128 * sizeof(float), stream);
  stats64<<<dim3(128), blk, 0, stream>>>(acc, st);
  apply64<<<GRID(NN * 16), blk, 0, stream>>>(acc, t0b, st, nullptr, dat, cur16, 1, 1);

  const int GBB = (NN + 127) / 128;  // 391
  auto tag16 = [&](const _Float16* src, const float* W) {
    prop16<<<GRID(NN * 8), blk, 0, stream>>>(rowptr, pme, src, h1);
    prop16<<<GRID(NN * 8), blk, 0, stream>>>(rowptr, pme, h1, h2);
    prop16<<<GRID(NN * 8), blk, 0, stream>>>(rowptr, pme, h2, h3);
    gemmB_mfma<<<dim3(GBB), dim3(128), 0, stream>>>(src, h1, h2, h3, W, acc);
  };

  // ---- residual blocks ----
  for (int i = 0; i < 2; i++) {
    tag16(cur16, tw + (2 * i) * 16384);
    apply64<<<GRID(NN * 16), blk, 0, stream>>>(acc, tb + (2 * i) * 64, nullptr, nullptr,
                                               nullptr, mid16, 0, 1);
    tag16(mid16, tw + (2 * i + 1) * 16384);
    hipMemsetAsync(st, 0, 128 * sizeof(float), stream);
    stats64<<<dim3(128), blk, 0, stream>>>(acc, st);
    apply64<<<GRID(NN * 16), blk, 0, stream>>>(acc, tb + (2 * i + 1) * 64, st, dat,
                                               dat, cur16, 1, 1);
  }
  // ---- final tagconv (no norm) ----
  tag16(cur16, tw + 4 * 16384);
  apply64<<<GRID(NN * 16), blk, 0, stream>>>(acc, tb + 4 * 64, nullptr, dat,
                                             nullptr, cur16, 0, 1);

  // ---- edge MLP (MFMA, f16 features) ----
  edge_mlp_mfma<<<GRID(NE), blk, 0, stream>>>(cur16, row, col, ew, We0, be0, g0, b0,
                                              Wa, ba, Wb, bb, lg, lb, Wf, bf, eout);
  hipMemsetAsync(est, 0, 2 * sizeof(float), stream);
  reduce2<<<dim3(1024), blk, 0, stream>>>(eout, est);
  finalize<<<GRID(NE), blk, 0, stream>>>(eout, est, (float*)d_out);
#undef GRID
}